// Round 2
// baseline (711.200 us; speedup 1.0000x reference)
//
#include <hip/hip_runtime.h>

// RWKV v7 TimeMix forward, MI355X gfx950.
// B=8 T=2048 C=1024 H=16 D=64 DLOW=64. I/O f32, internal compute bf16 MFMA + f32 scan.

typedef __bf16 bf16;
typedef __attribute__((ext_vector_type(8))) __bf16 bf16x8;
typedef __attribute__((ext_vector_type(4))) float f32x4;

#define TBTOK 16384   // B*T
#define TSEQ  2048
#define CDIM  1024
#define HN    16

__device__ __forceinline__ float wredsum(float v) {
#pragma unroll
  for (int o = 32; o > 0; o >>= 1) v += __shfl_xor(v, o, 64);
  return v;
}
__device__ __forceinline__ float sigmf(float x) { return 1.f / (1.f + expf(-x)); }

// ---------------- transpose f32 -> bf16 ----------------
__global__ __launch_bounds__(256) void transpose_cvt(const float* __restrict__ src,
                                                     bf16* __restrict__ dst,
                                                     int R, int Cc) {
  __shared__ bf16 tile[32][33];
  int x = blockIdx.x * 32 + threadIdx.x;
  int y0 = blockIdx.y * 32 + threadIdx.y;
#pragma unroll
  for (int i = 0; i < 32; i += 8)
    tile[threadIdx.y + i][threadIdx.x] = (bf16)src[(long)(y0 + i) * Cc + x];
  __syncthreads();
  int xo = blockIdx.y * 32 + threadIdx.x;
  int yo = blockIdx.x * 32 + threadIdx.y;
#pragma unroll
  for (int i = 0; i < 32; i += 8)
    dst[(long)(yo + i) * R + xo] = tile[threadIdx.x][threadIdx.y + i];
}

// ---------------- big GEMM: 128x128 tile, BK=32, 4 waves of 64x64 ----------------
// AT=float (with optional token-shift mix) or bf16. OT=bf16 or float.
template <int SHIFT, int ACT, typename AT, typename OT>  // ACT: 0 none, 1 sigmoid
__global__ __launch_bounds__(256) void gemm128_kern(
    const AT* __restrict__ A, int apitch, int acol0,
    const bf16* __restrict__ BT0, const bf16* __restrict__ BT1, const bf16* __restrict__ BT2,
    const float* __restrict__ mix0, const float* __restrict__ mix1, const float* __restrict__ mix2,
    OT* __restrict__ out0, OT* __restrict__ out1, OT* __restrict__ out2,
    int opitch, int K, int nbpm) {
  int by = blockIdx.y;
  int mat = by / nbpm;
  int ncol0 = (by % nbpm) * 128;
  const bf16* BTm = mat == 0 ? BT0 : (mat == 1 ? BT1 : BT2);
  const float* mix = mat == 0 ? mix0 : (mat == 1 ? mix1 : mix2);
  OT* out = mat == 0 ? out0 : (mat == 1 ? out1 : out2);
  int m0 = blockIdx.x * 128;

  __shared__ bf16 Al[128 * 40];
  __shared__ bf16 Bl[128 * 40];

  int tid = threadIdx.x;
  int w = tid >> 6, lane = tid & 63, quad = lane >> 4, lr = lane & 15;
  int wm = (w & 1) * 64, wn = (w >> 1) * 64;

  f32x4 acc[4][4] = {};

  int srow = tid >> 2;        // 0..63
  int kc = (tid & 3) * 8;     // 0,8,16,24

  for (int k0 = 0; k0 < K; k0 += 32) {
#pragma unroll
    for (int rr = 0; rr < 128; rr += 64) {
      int row = srow + rr;
      int m = m0 + row;
      bf16x8 av;
      if constexpr (sizeof(AT) == 4) {
        const float* ap = (const float*)A + (long)m * apitch + acol0 + k0 + kc;
        f32x4 x0 = *(const f32x4*)ap;
        f32x4 x1 = *(const f32x4*)(ap + 4);
        if (SHIFT) {
          // prev token is ZERO at sequence start: sx = x - prev
          bool first = (m & (TSEQ - 1)) == 0;
          f32x4 p0 = {0.f, 0.f, 0.f, 0.f}, p1 = {0.f, 0.f, 0.f, 0.f};
          if (!first) {
            p0 = *(const f32x4*)(ap - apitch);
            p1 = *(const f32x4*)(ap - apitch + 4);
          }
          const float* mx = mix + k0 + kc;
#pragma unroll
          for (int j = 0; j < 4; j++) av[j] = (bf16)(x0[j] + (x0[j] - p0[j]) * mx[j]);
#pragma unroll
          for (int j = 0; j < 4; j++) av[4 + j] = (bf16)(x1[j] + (x1[j] - p1[j]) * mx[4 + j]);
        } else {
#pragma unroll
          for (int j = 0; j < 4; j++) { av[j] = (bf16)x0[j]; av[4 + j] = (bf16)x1[j]; }
        }
      } else {
        const bf16* ap = (const bf16*)A + (long)m * apitch + acol0 + k0 + kc;
        av = *(const bf16x8*)ap;
      }
      *(bf16x8*)&Al[row * 40 + kc] = av;
      const bf16* bp = BTm + (long)(ncol0 + row) * K + k0 + kc;
      *(bf16x8*)&Bl[row * 40 + kc] = *(const bf16x8*)bp;
    }
    __syncthreads();
    bf16x8 af[4], bff[4];
#pragma unroll
    for (int i = 0; i < 4; i++) af[i] = *(const bf16x8*)&Al[(wm + i * 16 + lr) * 40 + quad * 8];
#pragma unroll
    for (int j = 0; j < 4; j++) bff[j] = *(const bf16x8*)&Bl[(wn + j * 16 + lr) * 40 + quad * 8];
#pragma unroll
    for (int i = 0; i < 4; i++)
#pragma unroll
      for (int j = 0; j < 4; j++)
        acc[i][j] = __builtin_amdgcn_mfma_f32_16x16x32_bf16(af[i], bff[j], acc[i][j], 0, 0, 0);
    __syncthreads();
  }
#pragma unroll
  for (int i = 0; i < 4; i++)
#pragma unroll
    for (int j = 0; j < 4; j++)
#pragma unroll
      for (int rg = 0; rg < 4; rg++) {
        int row = m0 + wm + i * 16 + quad * 4 + rg;
        int col = ncol0 + wn + j * 16 + lr;
        float v = acc[i][j][rg];
        if (ACT == 1) v = sigmf(v);
        out[(long)row * opitch + col] = (OT)v;
      }
}

// ---------------- LoRA stage1: [M,1024]@[1024,64]x3 with shift + tanh ----------------
// tile 128(M)x64(N), 4 waves of 32x64. out t1[m][mat*64+c] bf16, pitch 192.
__global__ __launch_bounds__(256) void gemm_stage1(
    const float* __restrict__ x,
    const bf16* __restrict__ BT0, const bf16* __restrict__ BT1, const bf16* __restrict__ BT2,
    const float* __restrict__ mix0, const float* __restrict__ mix1, const float* __restrict__ mix2,
    bf16* __restrict__ t1) {
  int mat = blockIdx.y;
  const bf16* BTm = mat == 0 ? BT0 : (mat == 1 ? BT1 : BT2);
  const float* mix = mat == 0 ? mix0 : (mat == 1 ? mix1 : mix2);
  int m0 = blockIdx.x * 128;

  __shared__ bf16 Al[128 * 40];
  __shared__ bf16 Bl[64 * 40];

  int tid = threadIdx.x;
  int w = tid >> 6, lane = tid & 63, quad = lane >> 4, lr = lane & 15;
  int wm = w * 32;

  f32x4 acc[2][4] = {};
  int srow = tid >> 2;
  int kc = (tid & 3) * 8;

  for (int k0 = 0; k0 < 1024; k0 += 32) {
#pragma unroll
    for (int rr = 0; rr < 128; rr += 64) {
      int row = srow + rr;
      int m = m0 + row;
      const float* ap = x + (long)m * CDIM + k0 + kc;
      f32x4 x0 = *(const f32x4*)ap;
      f32x4 x1 = *(const f32x4*)(ap + 4);
      bool first = (m & (TSEQ - 1)) == 0;
      f32x4 p0 = {0.f, 0.f, 0.f, 0.f}, p1 = {0.f, 0.f, 0.f, 0.f};
      if (!first) {
        p0 = *(const f32x4*)(ap - CDIM);
        p1 = *(const f32x4*)(ap - CDIM + 4);
      }
      const float* mx = mix + k0 + kc;
      bf16x8 av;
#pragma unroll
      for (int j = 0; j < 4; j++) av[j] = (bf16)(x0[j] + (x0[j] - p0[j]) * mx[j]);
#pragma unroll
      for (int j = 0; j < 4; j++) av[4 + j] = (bf16)(x1[j] + (x1[j] - p1[j]) * mx[4 + j]);
      *(bf16x8*)&Al[row * 40 + kc] = av;
    }
    // B tile: 64 rows x 32 k, exactly 256 thread-chunks
    *(bf16x8*)&Bl[srow * 40 + kc] = *(const bf16x8*)(BTm + (long)srow * 1024 + k0 + kc);
    __syncthreads();
    bf16x8 af[2], bff[4];
#pragma unroll
    for (int i = 0; i < 2; i++) af[i] = *(const bf16x8*)&Al[(wm + i * 16 + lr) * 40 + quad * 8];
#pragma unroll
    for (int j = 0; j < 4; j++) bff[j] = *(const bf16x8*)&Bl[(j * 16 + lr) * 40 + quad * 8];
#pragma unroll
    for (int i = 0; i < 2; i++)
#pragma unroll
      for (int j = 0; j < 4; j++)
        acc[i][j] = __builtin_amdgcn_mfma_f32_16x16x32_bf16(af[i], bff[j], acc[i][j], 0, 0, 0);
    __syncthreads();
  }
#pragma unroll
  for (int i = 0; i < 2; i++)
#pragma unroll
    for (int j = 0; j < 4; j++)
#pragma unroll
      for (int rg = 0; rg < 4; rg++) {
        int row = m0 + wm + i * 16 + quad * 4 + rg;
        int col = mat * 64 + j * 16 + lr;
        t1[(long)row * 192 + col] = (bf16)tanhf(acc[i][j][rg]);
      }
}

// ---------------- stage2 w/a: tiny K=64,N=16 dots ----------------
__global__ __launch_bounds__(256) void stage2_wa(
    const bf16* __restrict__ t1, const float* __restrict__ w2, const float* __restrict__ a2,
    const float* __restrict__ w0, const float* __restrict__ a0,
    float* __restrict__ w_arr, float* __restrict__ a_arr) {
  int tid = blockIdx.x * 256 + threadIdx.x;  // BT*16 threads
  int m = tid >> 4, h = tid & 15;
  float dw = 0.f, da = 0.f;
  const bf16* rw = t1 + (long)m * 192;
  const bf16* ra = rw + 64;
#pragma unroll 8
  for (int k = 0; k < 64; k++) {
    dw += (float)rw[k] * w2[k * 16 + h];
    da += (float)ra[k] * a2[k * 16 + h];
  }
  // w = exp(-softplus(-(w0+dw)) - 0.5) = sigmoid(w0+dw) * exp(-0.5)
  w_arr[h * TBTOK + m] = 0.60653066f * sigmf(w0[h] + dw);
  a_arr[h * TBTOK + m] = sigmf(a0[h] + da);
}

// ---------------- prep: kk-normalize, kv, bonus coeff. wave per (m,h) ----------------
__global__ __launch_bounds__(256) void prep_kern(
    const bf16* __restrict__ k_buf, const bf16* __restrict__ v_buf, const bf16* __restrict__ r_buf,
    const float* __restrict__ k_k, const float* __restrict__ r_k, const float* __restrict__ a_arr,
    float* __restrict__ kv2, float* __restrict__ bonus) {
  int wid = blockIdx.x * 4 + (threadIdx.x >> 6);
  int lane = threadIdx.x & 63;
  int m = wid >> 4, h = wid & 15;
  int c = h * 64 + lane;
  float kf = (float)k_buf[(long)m * CDIM + c] * k_k[c];
  float ss = wredsum(kf * kf);
  float kkn = kf / fmaxf(sqrtf(ss), 1e-12f);
  float vf = (float)v_buf[(long)m * CDIM + c];
  float af = a_arr[h * TBTOK + m];
  kv2[((long)h * TBTOK + m) * 64 + lane] = kkn * vf * af;
  float rf = (float)r_buf[(long)m * CDIM + c];
  float bs = wredsum(rf * kkn * r_k[c]);
  if (lane == 0) bonus[m * HN + h] = bs;
}

// ---------------- scan: state = state*w + kv, in place. block per (b,h) ----------------
__global__ __launch_bounds__(64) void scan_kern(float* __restrict__ kv2,
                                                const float* __restrict__ w_arr) {
  int bh = blockIdx.x;  // 128
  int b = bh >> 4, h = bh & 15;
  int d = threadIdx.x;
  long base = ((long)h * TBTOK + (long)b * TSEQ) * 64 + d;
  int wb = h * TBTOK + b * TSEQ;
  float st = 0.f;
  for (int t = 0; t < TSEQ; t += 4) {
    float c0 = kv2[base], c1 = kv2[base + 64], c2 = kv2[base + 128], c3 = kv2[base + 192];
    float d0 = w_arr[wb + t], d1 = w_arr[wb + t + 1], d2 = w_arr[wb + t + 2], d3 = w_arr[wb + t + 3];
    st = st * d0 + c0; kv2[base] = st;
    st = st * d1 + c1; kv2[base + 64] = st;
    st = st * d2 + c2; kv2[base + 128] = st;
    st = st * d3 + c3; kv2[base + 192] = st;
    base += 256;
  }
}

// ---------------- post: x_wkv*r + bonus*v, GroupNorm(D=64), *ln, *g -> an (into r_buf) ----
__global__ __launch_bounds__(256) void post_kern(
    const float* __restrict__ states, bf16* __restrict__ r_buf, const bf16* __restrict__ v_buf,
    const float* __restrict__ bonus, const bf16* __restrict__ g_buf,
    const float* __restrict__ ln_w, const float* __restrict__ ln_b) {
  int wid = blockIdx.x * 4 + (threadIdx.x >> 6);
  int lane = threadIdx.x & 63;
  int m = wid >> 4, h = wid & 15;
  int c = h * 64 + lane;
  float st = states[((long)h * TBTOK + m) * 64 + lane];
  float rf = (float)r_buf[(long)m * CDIM + c];
  float vf = (float)v_buf[(long)m * CDIM + c];
  float bs = bonus[m * HN + h];
  float xw = st * rf + bs * vf;
  float mn = wredsum(xw) * (1.f / 64.f);
  float dv = xw - mn;
  float var = wredsum(dv * dv) * (1.f / 64.f);
  float xn = dv * rsqrtf(var + 1e-5f);
  float y = xn * ln_w[c] + ln_b[c];
  r_buf[(long)m * CDIM + c] = (bf16)(y * (float)g_buf[(long)m * CDIM + c]);
}

extern "C" void kernel_launch(void* const* d_in, const int* in_sizes, int n_in,
                              void* d_out, int out_size, void* d_ws, size_t ws_size,
                              hipStream_t stream) {
  const float* x    = (const float*)d_in[0];
  const float* x_r  = (const float*)d_in[1];
  const float* x_w  = (const float*)d_in[2];
  const float* x_k  = (const float*)d_in[3];
  const float* x_v  = (const float*)d_in[4];
  const float* x_a  = (const float*)d_in[5];
  const float* x_g  = (const float*)d_in[6];
  const float* w0   = (const float*)d_in[7];
  const float* w1   = (const float*)d_in[8];
  const float* w2   = (const float*)d_in[9];
  const float* a0   = (const float*)d_in[10];
  const float* a1   = (const float*)d_in[11];
  const float* a2   = (const float*)d_in[12];
  // v0,v1,v2 (13,14,15) unused: v_res_gate is a no-op in the reference
  const float* g1   = (const float*)d_in[16];
  const float* g2   = (const float*)d_in[17];
  const float* k_k  = (const float*)d_in[18];
  const float* r_k  = (const float*)d_in[19];
  const float* Wr   = (const float*)d_in[20];
  const float* Wk   = (const float*)d_in[21];
  const float* Wv   = (const float*)d_in[22];
  const float* Wo   = (const float*)d_in[23];
  const float* ln_w = (const float*)d_in[24];
  const float* ln_b = (const float*)d_in[25];
  float* out = (float*)d_out;

  // ---- carve workspace (~210 MB) ----
  char* p = (char*)d_ws;
  auto carve = [&](size_t bytes) {
    void* r = (void*)p;
    p += (bytes + 255) & ~(size_t)255;
    return r;
  };
  bf16* WrT = (bf16*)carve(1024 * 1024 * 2);
  bf16* WkT = (bf16*)carve(1024 * 1024 * 2);
  bf16* WvT = (bf16*)carve(1024 * 1024 * 2);
  bf16* WoT = (bf16*)carve(1024 * 1024 * 2);
  bf16* w1T = (bf16*)carve(64 * 1024 * 2);
  bf16* a1T = (bf16*)carve(64 * 1024 * 2);
  bf16* g1T = (bf16*)carve(64 * 1024 * 2);
  bf16* g2T = (bf16*)carve(1024 * 64 * 2);
  bf16* t1    = (bf16*)carve((size_t)TBTOK * 192 * 2);
  bf16* r_buf = (bf16*)carve((size_t)TBTOK * CDIM * 2);  // later reused as `an`
  bf16* k_buf = (bf16*)carve((size_t)TBTOK * CDIM * 2);
  bf16* v_buf = (bf16*)carve((size_t)TBTOK * CDIM * 2);
  bf16* g_buf = (bf16*)carve((size_t)TBTOK * CDIM * 2);
  float* w_arr = (float*)carve((size_t)TBTOK * HN * 4);
  float* a_arr = (float*)carve((size_t)TBTOK * HN * 4);
  float* bonus = (float*)carve((size_t)TBTOK * HN * 4);
  float* kv2   = (float*)carve((size_t)TBTOK * CDIM * 4);  // scan runs in-place -> states

  dim3 tb(32, 8);
  // weight transposes+convert ([K,N] f32 -> [N,K] bf16)
  transpose_cvt<<<dim3(32, 32), tb, 0, stream>>>(Wr, WrT, 1024, 1024);
  transpose_cvt<<<dim3(32, 32), tb, 0, stream>>>(Wk, WkT, 1024, 1024);
  transpose_cvt<<<dim3(32, 32), tb, 0, stream>>>(Wv, WvT, 1024, 1024);
  transpose_cvt<<<dim3(32, 32), tb, 0, stream>>>(Wo, WoT, 1024, 1024);
  transpose_cvt<<<dim3(2, 32), tb, 0, stream>>>(w1, w1T, 1024, 64);
  transpose_cvt<<<dim3(2, 32), tb, 0, stream>>>(a1, a1T, 1024, 64);
  transpose_cvt<<<dim3(2, 32), tb, 0, stream>>>(g1, g1T, 1024, 64);
  transpose_cvt<<<dim3(32, 2), tb, 0, stream>>>(g2, g2T, 64, 1024);

  // LoRA stage1: t1 = tanh(shiftmix(x) @ {w1,a1,g1})
  gemm_stage1<<<dim3(TBTOK / 128, 3), 256, 0, stream>>>(x, w1T, a1T, g1T, x_w, x_a, x_g, t1);
  // stage2 w,a
  stage2_wa<<<dim3(TBTOK * HN / 256), 256, 0, stream>>>(t1, w2, a2, w0, a0, w_arr, a_arr);
  // gate: g = sigmoid(t1g @ g2)
  gemm128_kern<0, 1, bf16, bf16><<<dim3(TBTOK / 128, 8), 256, 0, stream>>>(
      t1, 192, 128, g2T, g2T, g2T, nullptr, nullptr, nullptr,
      g_buf, g_buf, g_buf, CDIM, 64, 8);
  // r,k,v projections with fused token-shift
  gemm128_kern<1, 0, float, bf16><<<dim3(TBTOK / 128, 24), 256, 0, stream>>>(
      x, CDIM, 0, WrT, WkT, WvT, x_r, x_k, x_v,
      r_buf, k_buf, v_buf, CDIM, 1024, 8);
  // kk normalize, kv, bonus
  prep_kern<<<dim3(TBTOK * HN / 4), 256, 0, stream>>>(k_buf, v_buf, r_buf, k_k, r_k, a_arr, kv2, bonus);
  // WKV scan (in place)
  scan_kern<<<dim3(8 * HN), 64, 0, stream>>>(kv2, w_arr);
  // epilogue: groupnorm + gate -> an (into r_buf)
  post_kern<<<dim3(TBTOK * HN / 4), 256, 0, stream>>>(kv2, r_buf, v_buf, bonus, g_buf, ln_w, ln_b);
  // out = an @ Wo  (f32 output)
  gemm128_kern<0, 0, bf16, float><<<dim3(TBTOK / 128, 8), 256, 0, stream>>>(
      r_buf, CDIM, 0, WoT, WoT, WoT, nullptr, nullptr, nullptr,
      out, out, out, CDIM, 1024, 8);
}

// Round 3
// 658.303 us; speedup vs baseline: 1.0804x; 1.0804x over previous
//
#include <hip/hip_runtime.h>

// RWKV v7 TimeMix forward, MI355X gfx950.
// B=8 T=2048 C=1024 H=16 D=64 DLOW=64. I/O f32, internal bf16 MFMA + f32 scan.
// R3: token-shift prepass -> bf16; m97-style GEMM with global_load_lds(16B).

typedef __bf16 bf16;
typedef __attribute__((ext_vector_type(8))) __bf16 bf16x8;
typedef __attribute__((ext_vector_type(4))) __bf16 bf16x4;
typedef __attribute__((ext_vector_type(4))) float f32x4;

#define TBTOK 16384   // B*T
#define TSEQ  2048
#define CDIM  1024
#define HN    16

__device__ __forceinline__ float wredsum(float v) {
#pragma unroll
  for (int o = 32; o > 0; o >>= 1) v += __shfl_xor(v, o, 64);
  return v;
}
__device__ __forceinline__ float sigmf(float x) { return 1.f / (1.f + expf(-x)); }

// async global->LDS, 16 bytes/lane. lptr must be wave-uniform (HW adds lane*16).
__device__ __forceinline__ void gl_lds16(const bf16* g, bf16* l) {
  __builtin_amdgcn_global_load_lds(
      (const __attribute__((address_space(1))) unsigned int*)g,
      (__attribute__((address_space(3))) unsigned int*)l, 16, 0, 0);
}

// ---------------- transpose f32 -> bf16 ----------------
__global__ __launch_bounds__(256) void transpose_cvt(const float* __restrict__ src,
                                                     bf16* __restrict__ dst,
                                                     int R, int Cc) {
  __shared__ bf16 tile[32][33];
  int x = blockIdx.x * 32 + threadIdx.x;
  int y0 = blockIdx.y * 32 + threadIdx.y;
#pragma unroll
  for (int i = 0; i < 32; i += 8)
    tile[threadIdx.y + i][threadIdx.x] = (bf16)src[(long)(y0 + i) * Cc + x];
  __syncthreads();
  int xo = blockIdx.y * 32 + threadIdx.x;
  int yo = blockIdx.x * 32 + threadIdx.y;
#pragma unroll
  for (int i = 0; i < 32; i += 8)
    dst[(long)(yo + i) * R + xo] = tile[threadIdx.x][threadIdx.y + i];
}

// ---------------- prepass: token-shift mix for r,k,v -> bf16 ----------------
__global__ __launch_bounds__(256) void mix3_kern(
    const float* __restrict__ x, const float* __restrict__ mr,
    const float* __restrict__ mk, const float* __restrict__ mv,
    bf16* __restrict__ xr, bf16* __restrict__ xk, bf16* __restrict__ xv) {
  long i4 = ((long)blockIdx.x * 256 + threadIdx.x) * 4;
  int m = (int)(i4 >> 10);
  int c = (int)(i4 & 1023);
  f32x4 xc = *(const f32x4*)(x + i4);
  f32x4 p = {0.f, 0.f, 0.f, 0.f};
  if ((m & (TSEQ - 1)) != 0) p = *(const f32x4*)(x + i4 - CDIM);
  f32x4 vr = *(const f32x4*)(mr + c);
  f32x4 vk = *(const f32x4*)(mk + c);
  f32x4 vv = *(const f32x4*)(mv + c);
  bf16x4 or_, ok_, ov_;
#pragma unroll
  for (int j = 0; j < 4; j++) {
    float s = xc[j] - p[j];
    or_[j] = (bf16)(xc[j] + s * vr[j]);
    ok_[j] = (bf16)(xc[j] + s * vk[j]);
    ov_[j] = (bf16)(xc[j] + s * vv[j]);
  }
  *(bf16x4*)(xr + i4) = or_;
  *(bf16x4*)(xk + i4) = ok_;
  *(bf16x4*)(xv + i4) = ov_;
}

// ---------------- m97-style GEMM: 128x128 tile, BK=32, global_load_lds staging ----------
// A bf16 [M,apitch] (+acol0), BT bf16 [N,K]. 4 waves of 64x64. ACT: 0 none, 1 sigmoid.
template <int ACT, typename OT>
__global__ __launch_bounds__(256) void gemm128_kern(
    const bf16* __restrict__ A0, const bf16* __restrict__ A1, const bf16* __restrict__ A2,
    int apitch, int acol0,
    const bf16* __restrict__ BT0, const bf16* __restrict__ BT1, const bf16* __restrict__ BT2,
    OT* __restrict__ out0, OT* __restrict__ out1, OT* __restrict__ out2,
    int opitch, int K, int nbpm) {
  int by = blockIdx.y;
  int mat = by / nbpm;
  int ncol0 = (by % nbpm) * 128;
  const bf16* Am = mat == 0 ? A0 : (mat == 1 ? A1 : A2);
  const bf16* BTm = mat == 0 ? BT0 : (mat == 1 ? BT1 : BT2);
  OT* out = mat == 0 ? out0 : (mat == 1 ? out1 : out2);
  int m0 = blockIdx.x * 128;

  __shared__ bf16 Al[128 * 32];  // unpadded: required by global_load_lds lane order
  __shared__ bf16 Bl[128 * 32];

  int tid = threadIdx.x;
  int w = tid >> 6, lane = tid & 63, quad = lane >> 4, lr = lane & 15;
  int wm = (w & 1) * 64, wn = (w >> 1) * 64;

  f32x4 acc[4][4] = {};

  // staging: chunk c = issue*256 + tid; row=c>>2, kc=(c&3)*8; LDS byte = c*16
  int r0 = tid >> 2, kc0 = (tid & 3) * 8;
  const bf16* ag0 = Am + (long)(m0 + r0) * apitch + acol0 + kc0;
  const bf16* ag1 = ag0 + (long)64 * apitch;
  const bf16* bg0 = BTm + (long)(ncol0 + r0) * K + kc0;
  const bf16* bg1 = bg0 + (long)64 * K;
  bf16* la0 = Al + w * 512;          // issue0 wave base (bytes w*1024)
  bf16* la1 = Al + 2048 + w * 512;   // issue1 (bytes 4096 + w*1024)
  bf16* lb0 = Bl + w * 512;
  bf16* lb1 = Bl + 2048 + w * 512;

  for (int k0 = 0; k0 < K; k0 += 32) {
    gl_lds16(ag0, la0);
    gl_lds16(ag1, la1);
    gl_lds16(bg0, lb0);
    gl_lds16(bg1, lb1);
    ag0 += 32; ag1 += 32; bg0 += 32; bg1 += 32;
    __syncthreads();
    bf16x8 af[4], bff[4];
#pragma unroll
    for (int i = 0; i < 4; i++) af[i] = *(const bf16x8*)&Al[(wm + i * 16 + lr) * 32 + quad * 8];
#pragma unroll
    for (int j = 0; j < 4; j++) bff[j] = *(const bf16x8*)&Bl[(wn + j * 16 + lr) * 32 + quad * 8];
#pragma unroll
    for (int i = 0; i < 4; i++)
#pragma unroll
      for (int j = 0; j < 4; j++)
        acc[i][j] = __builtin_amdgcn_mfma_f32_16x16x32_bf16(af[i], bff[j], acc[i][j], 0, 0, 0);
    __syncthreads();
  }
#pragma unroll
  for (int i = 0; i < 4; i++)
#pragma unroll
    for (int j = 0; j < 4; j++)
#pragma unroll
      for (int rg = 0; rg < 4; rg++) {
        int row = m0 + wm + i * 16 + quad * 4 + rg;
        int col = ncol0 + wn + j * 16 + lr;
        float v = acc[i][j][rg];
        if (ACT == 1) v = sigmf(v);
        out[(long)row * opitch + col] = (OT)v;
      }
}

// ---------------- LoRA stage1: [M,1024]@[1024,64]x3 with f32 shift-mix + tanh ----------
__global__ __launch_bounds__(256) void gemm_stage1(
    const float* __restrict__ x,
    const bf16* __restrict__ BT0, const bf16* __restrict__ BT1, const bf16* __restrict__ BT2,
    const float* __restrict__ mix0, const float* __restrict__ mix1, const float* __restrict__ mix2,
    bf16* __restrict__ t1) {
  int mat = blockIdx.y;
  const bf16* BTm = mat == 0 ? BT0 : (mat == 1 ? BT1 : BT2);
  const float* mix = mat == 0 ? mix0 : (mat == 1 ? mix1 : mix2);
  int m0 = blockIdx.x * 128;

  __shared__ bf16 Al[128 * 40];
  __shared__ bf16 Bl[64 * 40];

  int tid = threadIdx.x;
  int w = tid >> 6, lane = tid & 63, quad = lane >> 4, lr = lane & 15;
  int wm = w * 32;

  f32x4 acc[2][4] = {};
  int srow = tid >> 2;
  int kc = (tid & 3) * 8;

  for (int k0 = 0; k0 < 1024; k0 += 32) {
#pragma unroll
    for (int rr = 0; rr < 128; rr += 64) {
      int row = srow + rr;
      int m = m0 + row;
      const float* ap = x + (long)m * CDIM + k0 + kc;
      f32x4 x0 = *(const f32x4*)ap;
      f32x4 x1 = *(const f32x4*)(ap + 4);
      bool first = (m & (TSEQ - 1)) == 0;
      f32x4 p0 = {0.f, 0.f, 0.f, 0.f}, p1 = {0.f, 0.f, 0.f, 0.f};
      if (!first) {
        p0 = *(const f32x4*)(ap - CDIM);
        p1 = *(const f32x4*)(ap - CDIM + 4);
      }
      const float* mx = mix + k0 + kc;
      bf16x8 av;
#pragma unroll
      for (int j = 0; j < 4; j++) av[j] = (bf16)(x0[j] + (x0[j] - p0[j]) * mx[j]);
#pragma unroll
      for (int j = 0; j < 4; j++) av[4 + j] = (bf16)(x1[j] + (x1[j] - p1[j]) * mx[4 + j]);
      *(bf16x8*)&Al[row * 40 + kc] = av;
    }
    *(bf16x8*)&Bl[srow * 40 + kc] = *(const bf16x8*)(BTm + (long)srow * 1024 + k0 + kc);
    __syncthreads();
    bf16x8 af[2], bff[4];
#pragma unroll
    for (int i = 0; i < 2; i++) af[i] = *(const bf16x8*)&Al[(wm + i * 16 + lr) * 40 + quad * 8];
#pragma unroll
    for (int j = 0; j < 4; j++) bff[j] = *(const bf16x8*)&Bl[(j * 16 + lr) * 40 + quad * 8];
#pragma unroll
    for (int i = 0; i < 2; i++)
#pragma unroll
      for (int j = 0; j < 4; j++)
        acc[i][j] = __builtin_amdgcn_mfma_f32_16x16x32_bf16(af[i], bff[j], acc[i][j], 0, 0, 0);
    __syncthreads();
  }
#pragma unroll
  for (int i = 0; i < 2; i++)
#pragma unroll
    for (int j = 0; j < 4; j++)
#pragma unroll
      for (int rg = 0; rg < 4; rg++) {
        int row = m0 + wm + i * 16 + quad * 4 + rg;
        int col = mat * 64 + j * 16 + lr;
        t1[(long)row * 192 + col] = (bf16)tanhf(acc[i][j][rg]);
      }
}

// ---------------- stage2 w/a: tiny K=64,N=16 dots ----------------
__global__ __launch_bounds__(256) void stage2_wa(
    const bf16* __restrict__ t1, const float* __restrict__ w2, const float* __restrict__ a2,
    const float* __restrict__ w0, const float* __restrict__ a0,
    float* __restrict__ w_arr, float* __restrict__ a_arr) {
  int tid = blockIdx.x * 256 + threadIdx.x;  // BT*16 threads
  int m = tid >> 4, h = tid & 15;
  float dw = 0.f, da = 0.f;
  const bf16* rw = t1 + (long)m * 192;
  const bf16* ra = rw + 64;
#pragma unroll 8
  for (int k = 0; k < 64; k++) {
    dw += (float)rw[k] * w2[k * 16 + h];
    da += (float)ra[k] * a2[k * 16 + h];
  }
  // w = exp(-softplus(-(w0+dw)) - 0.5) = sigmoid(w0+dw) * exp(-0.5)
  w_arr[h * TBTOK + m] = 0.60653066f * sigmf(w0[h] + dw);
  a_arr[h * TBTOK + m] = sigmf(a0[h] + da);
}

// ---------------- prep: kk-normalize, kv, bonus coeff. wave per (m,h) ----------------
__global__ __launch_bounds__(256) void prep_kern(
    const bf16* __restrict__ k_buf, const bf16* __restrict__ v_buf, const bf16* __restrict__ r_buf,
    const float* __restrict__ k_k, const float* __restrict__ r_k, const float* __restrict__ a_arr,
    float* __restrict__ kv2, float* __restrict__ bonus) {
  int wid = blockIdx.x * 4 + (threadIdx.x >> 6);
  int lane = threadIdx.x & 63;
  int m = wid >> 4, h = wid & 15;
  int c = h * 64 + lane;
  float kf = (float)k_buf[(long)m * CDIM + c] * k_k[c];
  float ss = wredsum(kf * kf);
  float kkn = kf / fmaxf(sqrtf(ss), 1e-12f);
  float vf = (float)v_buf[(long)m * CDIM + c];
  float af = a_arr[h * TBTOK + m];
  kv2[((long)h * TBTOK + m) * 64 + lane] = kkn * vf * af;
  float rf = (float)r_buf[(long)m * CDIM + c];
  float bs = wredsum(rf * kkn * r_k[c]);
  if (lane == 0) bonus[m * HN + h] = bs;
}

// ---------------- scan: state = state*w + kv, in place. block per (b,h) ----------------
__global__ __launch_bounds__(64) void scan_kern(float* __restrict__ kv2,
                                                const float* __restrict__ w_arr) {
  int bh = blockIdx.x;  // 128
  int b = bh >> 4, h = bh & 15;
  int d = threadIdx.x;
  long base = ((long)h * TBTOK + (long)b * TSEQ) * 64 + d;
  int wb = h * TBTOK + b * TSEQ;
  float st = 0.f;
  for (int t = 0; t < TSEQ; t += 4) {
    float c0 = kv2[base], c1 = kv2[base + 64], c2 = kv2[base + 128], c3 = kv2[base + 192];
    float d0 = w_arr[wb + t], d1 = w_arr[wb + t + 1], d2 = w_arr[wb + t + 2], d3 = w_arr[wb + t + 3];
    st = st * d0 + c0; kv2[base] = st;
    st = st * d1 + c1; kv2[base + 64] = st;
    st = st * d2 + c2; kv2[base + 128] = st;
    st = st * d3 + c3; kv2[base + 192] = st;
    base += 256;
  }
}

// ---------------- post: x_wkv*r + bonus*v, GroupNorm(D=64), *ln, *g -> an (into r_buf) ----
__global__ __launch_bounds__(256) void post_kern(
    const float* __restrict__ states, bf16* __restrict__ r_buf, const bf16* __restrict__ v_buf,
    const float* __restrict__ bonus, const bf16* __restrict__ g_buf,
    const float* __restrict__ ln_w, const float* __restrict__ ln_b) {
  int wid = blockIdx.x * 4 + (threadIdx.x >> 6);
  int lane = threadIdx.x & 63;
  int m = wid >> 4, h = wid & 15;
  int c = h * 64 + lane;
  float st = states[((long)h * TBTOK + m) * 64 + lane];
  float rf = (float)r_buf[(long)m * CDIM + c];
  float vf = (float)v_buf[(long)m * CDIM + c];
  float bs = bonus[m * HN + h];
  float xw = st * rf + bs * vf;
  float mn = wredsum(xw) * (1.f / 64.f);
  float dv = xw - mn;
  float var = wredsum(dv * dv) * (1.f / 64.f);
  float xn = dv * rsqrtf(var + 1e-5f);
  float y = xn * ln_w[c] + ln_b[c];
  r_buf[(long)m * CDIM + c] = (bf16)(y * (float)g_buf[(long)m * CDIM + c]);
}

extern "C" void kernel_launch(void* const* d_in, const int* in_sizes, int n_in,
                              void* d_out, int out_size, void* d_ws, size_t ws_size,
                              hipStream_t stream) {
  const float* x    = (const float*)d_in[0];
  const float* x_r  = (const float*)d_in[1];
  const float* x_w  = (const float*)d_in[2];
  const float* x_k  = (const float*)d_in[3];
  const float* x_v  = (const float*)d_in[4];
  const float* x_a  = (const float*)d_in[5];
  const float* x_g  = (const float*)d_in[6];
  const float* w0   = (const float*)d_in[7];
  const float* w1   = (const float*)d_in[8];
  const float* w2   = (const float*)d_in[9];
  const float* a0   = (const float*)d_in[10];
  const float* a1   = (const float*)d_in[11];
  const float* a2   = (const float*)d_in[12];
  // v0,v1,v2 (13,14,15) unused: v_res_gate is a no-op in the reference
  const float* g1   = (const float*)d_in[16];
  const float* g2   = (const float*)d_in[17];
  const float* k_k  = (const float*)d_in[18];
  const float* r_k  = (const float*)d_in[19];
  const float* Wr   = (const float*)d_in[20];
  const float* Wk   = (const float*)d_in[21];
  const float* Wv   = (const float*)d_in[22];
  const float* Wo   = (const float*)d_in[23];
  const float* ln_w = (const float*)d_in[24];
  const float* ln_b = (const float*)d_in[25];
  float* out = (float*)d_out;

  // ---- carve workspace (~210 MB, with aliasing) ----
  char* p = (char*)d_ws;
  auto carve = [&](size_t bytes) {
    void* r = (void*)p;
    p += (bytes + 255) & ~(size_t)255;
    return r;
  };
  bf16* WrT = (bf16*)carve(1024 * 1024 * 2);
  bf16* WkT = (bf16*)carve(1024 * 1024 * 2);
  bf16* WvT = (bf16*)carve(1024 * 1024 * 2);
  bf16* WoT = (bf16*)carve(1024 * 1024 * 2);
  bf16* w1T = (bf16*)carve(64 * 1024 * 2);
  bf16* a1T = (bf16*)carve(64 * 1024 * 2);
  bf16* g1T = (bf16*)carve(64 * 1024 * 2);
  bf16* g2T = (bf16*)carve(1024 * 64 * 2);
  bf16* t1    = (bf16*)carve((size_t)TBTOK * 192 * 2);
  bf16* r_buf = (bf16*)carve((size_t)TBTOK * CDIM * 2);  // later reused as `an`
  bf16* k_buf = (bf16*)carve((size_t)TBTOK * CDIM * 2);
  bf16* v_buf = (bf16*)carve((size_t)TBTOK * CDIM * 2);
  float* w_arr = (float*)carve((size_t)TBTOK * HN * 4);
  float* a_arr = (float*)carve((size_t)TBTOK * HN * 4);
  float* bonus = (float*)carve((size_t)TBTOK * HN * 4);
  // shifted bf16 inputs; xr+xk region is reused as kv2 (f32, 64MB) after rkv GEMM,
  // xv region reused as g_buf (gate GEMM runs after rkv GEMM).
  bf16* xr = (bf16*)carve((size_t)TBTOK * CDIM * 2);  // 32MB
  bf16* xk = (bf16*)carve((size_t)TBTOK * CDIM * 2);  // 32MB (contiguous with xr)
  bf16* xv = (bf16*)carve((size_t)TBTOK * CDIM * 2);  // 32MB
  float* kv2  = (float*)xr;   // 64MB = xr+xk, alive after rkv GEMM consumed them
  bf16*  g_buf = xv;          // 32MB, alive after rkv GEMM consumed xv

  dim3 tb(32, 8);
  // weight transposes+convert ([K,N] f32 -> [N,K] bf16)
  transpose_cvt<<<dim3(32, 32), tb, 0, stream>>>(Wr, WrT, 1024, 1024);
  transpose_cvt<<<dim3(32, 32), tb, 0, stream>>>(Wk, WkT, 1024, 1024);
  transpose_cvt<<<dim3(32, 32), tb, 0, stream>>>(Wv, WvT, 1024, 1024);
  transpose_cvt<<<dim3(32, 32), tb, 0, stream>>>(Wo, WoT, 1024, 1024);
  transpose_cvt<<<dim3(2, 32), tb, 0, stream>>>(w1, w1T, 1024, 64);
  transpose_cvt<<<dim3(2, 32), tb, 0, stream>>>(a1, a1T, 1024, 64);
  transpose_cvt<<<dim3(2, 32), tb, 0, stream>>>(g1, g1T, 1024, 64);
  transpose_cvt<<<dim3(32, 2), tb, 0, stream>>>(g2, g2T, 64, 1024);

  // token-shift prepass (r,k,v) -> bf16
  mix3_kern<<<dim3(TBTOK * CDIM / 1024), 256, 0, stream>>>(x, x_r, x_k, x_v, xr, xk, xv);
  // LoRA stage1: t1 = tanh(shiftmix(x) @ {w1,a1,g1})
  gemm_stage1<<<dim3(TBTOK / 128, 3), 256, 0, stream>>>(x, w1T, a1T, g1T, x_w, x_a, x_g, t1);
  // stage2 w,a
  stage2_wa<<<dim3(TBTOK * HN / 256), 256, 0, stream>>>(t1, w2, a2, w0, a0, w_arr, a_arr);
  // r,k,v projections (pure bf16, async staging)
  gemm128_kern<0, bf16><<<dim3(TBTOK / 128, 24), 256, 0, stream>>>(
      xr, xk, xv, CDIM, 0, WrT, WkT, WvT,
      r_buf, k_buf, v_buf, CDIM, 1024, 8);
  // gate: g = sigmoid(t1g @ g2)   (after rkv so g_buf can alias xv)
  gemm128_kern<1, bf16><<<dim3(TBTOK / 128, 8), 256, 0, stream>>>(
      t1, t1, t1, 192, 128, g2T, g2T, g2T,
      g_buf, g_buf, g_buf, CDIM, 64, 8);
  // kk normalize, kv, bonus (kv2 aliases dead xr/xk)
  prep_kern<<<dim3(TBTOK * HN / 4), 256, 0, stream>>>(k_buf, v_buf, r_buf, k_k, r_k, a_arr, kv2, bonus);
  // WKV scan (in place)
  scan_kern<<<dim3(8 * HN), 64, 0, stream>>>(kv2, w_arr);
  // epilogue: groupnorm + gate -> an (into r_buf)
  post_kern<<<dim3(TBTOK * HN / 4), 256, 0, stream>>>(kv2, r_buf, v_buf, bonus, g_buf, ln_w, ln_b);
  // out = an @ Wo  (f32 output)
  gemm128_kern<0, float><<<dim3(TBTOK / 128, 8), 256, 0, stream>>>(
      r_buf, r_buf, r_buf, CDIM, 0, WoT, WoT, WoT,
      out, out, out, CDIM, 1024, 8);
}

// Round 4
// 643.953 us; speedup vs baseline: 1.1044x; 1.0223x over previous
//
#include <hip/hip_runtime.h>

// RWKV v7 TimeMix forward, MI355X gfx950.
// B=8 T=2048 C=1024 H=16 D=64 DLOW=64. I/O f32, internal bf16 MFMA + f32 scan.
// R4: chunked parallel WKV scan (prep/post fused), merged 3-mat LoRA stage1.

typedef __bf16 bf16;
typedef __attribute__((ext_vector_type(8))) __bf16 bf16x8;
typedef __attribute__((ext_vector_type(4))) float f32x4;

#define TBTOK 16384   // B*T
#define TSEQ  2048
#define CDIM  1024
#define HN    16
#define CHUNK 64
#define NCH   32      // TSEQ / CHUNK

__device__ __forceinline__ float wredsum(float v) {
#pragma unroll
  for (int o = 32; o > 0; o >>= 1) v += __shfl_xor(v, o, 64);
  return v;
}
__device__ __forceinline__ float sigmf(float x) { return 1.f / (1.f + expf(-x)); }

// async global->LDS, 16 bytes/lane. LDS base wave-uniform (HW adds lane*16).
__device__ __forceinline__ void gl_lds16(const bf16* g, bf16* l) {
  __builtin_amdgcn_global_load_lds(
      (const __attribute__((address_space(1))) unsigned int*)g,
      (__attribute__((address_space(3))) unsigned int*)l, 16, 0, 0);
}

// ---------------- transpose f32 -> bf16 ----------------
__global__ __launch_bounds__(256) void transpose_cvt(const float* __restrict__ src,
                                                     bf16* __restrict__ dst,
                                                     int R, int Cc) {
  __shared__ bf16 tile[32][33];
  int x = blockIdx.x * 32 + threadIdx.x;
  int y0 = blockIdx.y * 32 + threadIdx.y;
#pragma unroll
  for (int i = 0; i < 32; i += 8)
    tile[threadIdx.y + i][threadIdx.x] = (bf16)src[(long)(y0 + i) * Cc + x];
  __syncthreads();
  int xo = blockIdx.y * 32 + threadIdx.x;
  int yo = blockIdx.x * 32 + threadIdx.y;
#pragma unroll
  for (int i = 0; i < 32; i += 8)
    dst[(long)(yo + i) * R + xo] = tile[threadIdx.x][threadIdx.y + i];
}

// ---------------- prepass: token-shift mix for r,k,v -> bf16 (8 elem/thread) -------
__global__ __launch_bounds__(256) void mix3_kern(
    const float* __restrict__ x, const float* __restrict__ mr,
    const float* __restrict__ mk, const float* __restrict__ mv,
    bf16* __restrict__ xr, bf16* __restrict__ xk, bf16* __restrict__ xv) {
  long i8 = ((long)blockIdx.x * 256 + threadIdx.x) * 8;
  int m = (int)(i8 >> 10);
  int c = (int)(i8 & 1023);
  f32x4 x0 = *(const f32x4*)(x + i8);
  f32x4 x1 = *(const f32x4*)(x + i8 + 4);
  f32x4 p0 = {0.f, 0.f, 0.f, 0.f}, p1 = {0.f, 0.f, 0.f, 0.f};
  if ((m & (TSEQ - 1)) != 0) {
    p0 = *(const f32x4*)(x + i8 - CDIM);
    p1 = *(const f32x4*)(x + i8 - CDIM + 4);
  }
  f32x4 r0 = *(const f32x4*)(mr + c), r1 = *(const f32x4*)(mr + c + 4);
  f32x4 k0 = *(const f32x4*)(mk + c), k1 = *(const f32x4*)(mk + c + 4);
  f32x4 v0 = *(const f32x4*)(mv + c), v1 = *(const f32x4*)(mv + c + 4);
  bf16x8 or_, ok_, ov_;
#pragma unroll
  for (int j = 0; j < 4; j++) {
    float s0 = x0[j] - p0[j], s1 = x1[j] - p1[j];
    or_[j] = (bf16)(x0[j] + s0 * r0[j]); or_[4 + j] = (bf16)(x1[j] + s1 * r1[j]);
    ok_[j] = (bf16)(x0[j] + s0 * k0[j]); ok_[4 + j] = (bf16)(x1[j] + s1 * k1[j]);
    ov_[j] = (bf16)(x0[j] + s0 * v0[j]); ov_[4 + j] = (bf16)(x1[j] + s1 * v1[j]);
  }
  *(bf16x8*)(xr + i8) = or_;
  *(bf16x8*)(xk + i8) = ok_;
  *(bf16x8*)(xv + i8) = ov_;
}

// ---------------- m97-style GEMM: 128x128 tile, BK=32, global_load_lds staging ----------
template <int ACT, typename OT>   // ACT: 0 none, 1 sigmoid
__global__ __launch_bounds__(256) void gemm128_kern(
    const bf16* __restrict__ A0, const bf16* __restrict__ A1, const bf16* __restrict__ A2,
    int apitch, int acol0,
    const bf16* __restrict__ BT0, const bf16* __restrict__ BT1, const bf16* __restrict__ BT2,
    OT* __restrict__ out0, OT* __restrict__ out1, OT* __restrict__ out2,
    int opitch, int K, int nbpm) {
  int by = blockIdx.y;
  int mat = by / nbpm;
  int ncol0 = (by % nbpm) * 128;
  const bf16* Am = mat == 0 ? A0 : (mat == 1 ? A1 : A2);
  const bf16* BTm = mat == 0 ? BT0 : (mat == 1 ? BT1 : BT2);
  OT* out = mat == 0 ? out0 : (mat == 1 ? out1 : out2);
  int m0 = blockIdx.x * 128;

  __shared__ bf16 Al[128 * 32];  // unpadded: required by global_load_lds lane order
  __shared__ bf16 Bl[128 * 32];

  int tid = threadIdx.x;
  int w = tid >> 6, lane = tid & 63, quad = lane >> 4, lr = lane & 15;
  int wm = (w & 1) * 64, wn = (w >> 1) * 64;

  f32x4 acc[4][4] = {};

  int r0 = tid >> 2, kc0 = (tid & 3) * 8;
  const bf16* ag0 = Am + (long)(m0 + r0) * apitch + acol0 + kc0;
  const bf16* ag1 = ag0 + (long)64 * apitch;
  const bf16* bg0 = BTm + (long)(ncol0 + r0) * K + kc0;
  const bf16* bg1 = bg0 + (long)64 * K;
  bf16* la0 = Al + w * 512;
  bf16* la1 = Al + 2048 + w * 512;
  bf16* lb0 = Bl + w * 512;
  bf16* lb1 = Bl + 2048 + w * 512;

  for (int k0 = 0; k0 < K; k0 += 32) {
    gl_lds16(ag0, la0);
    gl_lds16(ag1, la1);
    gl_lds16(bg0, lb0);
    gl_lds16(bg1, lb1);
    ag0 += 32; ag1 += 32; bg0 += 32; bg1 += 32;
    __syncthreads();
    bf16x8 af[4], bff[4];
#pragma unroll
    for (int i = 0; i < 4; i++) af[i] = *(const bf16x8*)&Al[(wm + i * 16 + lr) * 32 + quad * 8];
#pragma unroll
    for (int j = 0; j < 4; j++) bff[j] = *(const bf16x8*)&Bl[(wn + j * 16 + lr) * 32 + quad * 8];
#pragma unroll
    for (int i = 0; i < 4; i++)
#pragma unroll
      for (int j = 0; j < 4; j++)
        acc[i][j] = __builtin_amdgcn_mfma_f32_16x16x32_bf16(af[i], bff[j], acc[i][j], 0, 0, 0);
    __syncthreads();
  }
#pragma unroll
  for (int i = 0; i < 4; i++)
#pragma unroll
    for (int j = 0; j < 4; j++)
#pragma unroll
      for (int rg = 0; rg < 4; rg++) {
        int row = m0 + wm + i * 16 + quad * 4 + rg;
        int col = ncol0 + wn + j * 16 + lr;
        float v = acc[i][j][rg];
        if (ACT == 1) v = sigmf(v);
        out[(long)row * opitch + col] = (OT)v;
      }
}

// ---------------- merged LoRA stage1: 64-row tile, all 3 mats, shift fused ----------
__global__ __launch_bounds__(256) void gemm_stage1(
    const float* __restrict__ x,
    const bf16* __restrict__ BT0, const bf16* __restrict__ BT1, const bf16* __restrict__ BT2,
    const float* __restrict__ mix0, const float* __restrict__ mix1, const float* __restrict__ mix2,
    bf16* __restrict__ t1) {
  int m0 = blockIdx.x * 64;
  __shared__ bf16 Al[3][64 * 40];
  __shared__ bf16 Bl[192 * 40];

  int tid = threadIdx.x;
  int w = tid >> 6, lane = tid & 63, quad = lane >> 4, lr = lane & 15;
  int wm = w * 16;

  const bf16* Bts[3] = {BT0, BT1, BT2};
  const float* mxs[3] = {mix0, mix1, mix2};

  f32x4 acc[3][4] = {};
  int srow = tid >> 2;
  int kc = (tid & 3) * 8;

  for (int k0 = 0; k0 < 1024; k0 += 32) {
    int m = m0 + srow;
    const float* ap = x + (long)m * CDIM + k0 + kc;
    f32x4 x0 = *(const f32x4*)ap;
    f32x4 x1 = *(const f32x4*)(ap + 4);
    f32x4 p0 = {0.f, 0.f, 0.f, 0.f}, p1 = {0.f, 0.f, 0.f, 0.f};
    if ((m & (TSEQ - 1)) != 0) {
      p0 = *(const f32x4*)(ap - CDIM);
      p1 = *(const f32x4*)(ap - CDIM + 4);
    }
#pragma unroll
    for (int mat = 0; mat < 3; mat++) {
      const float* mx = mxs[mat] + k0 + kc;
      bf16x8 av;
#pragma unroll
      for (int j = 0; j < 4; j++) {
        av[j] = (bf16)(x0[j] + (x0[j] - p0[j]) * mx[j]);
        av[4 + j] = (bf16)(x1[j] + (x1[j] - p1[j]) * mx[4 + j]);
      }
      *(bf16x8*)&Al[mat][srow * 40 + kc] = av;
      *(bf16x8*)&Bl[(mat * 64 + srow) * 40 + kc] =
          *(const bf16x8*)(Bts[mat] + (long)srow * 1024 + k0 + kc);
    }
    __syncthreads();
    bf16x8 af[3];
#pragma unroll
    for (int mat = 0; mat < 3; mat++)
      af[mat] = *(const bf16x8*)&Al[mat][(wm + lr) * 40 + quad * 8];
#pragma unroll
    for (int mat = 0; mat < 3; mat++)
#pragma unroll
      for (int j = 0; j < 4; j++) {
        bf16x8 bff = *(const bf16x8*)&Bl[(mat * 64 + j * 16 + lr) * 40 + quad * 8];
        acc[mat][j] = __builtin_amdgcn_mfma_f32_16x16x32_bf16(af[mat], bff, acc[mat][j], 0, 0, 0);
      }
    __syncthreads();
  }
#pragma unroll
  for (int mat = 0; mat < 3; mat++)
#pragma unroll
    for (int j = 0; j < 4; j++)
#pragma unroll
      for (int rg = 0; rg < 4; rg++) {
        int row = m0 + wm + quad * 4 + rg;
        int col = mat * 64 + j * 16 + lr;
        t1[(long)row * 192 + col] = (bf16)tanhf(acc[mat][j][rg]);
      }
}

// ---------------- stage2 w/a: tiny K=64,N=16 dots ----------------
__global__ __launch_bounds__(256) void stage2_wa(
    const bf16* __restrict__ t1, const float* __restrict__ w2, const float* __restrict__ a2,
    const float* __restrict__ w0, const float* __restrict__ a0,
    float* __restrict__ w_arr, float* __restrict__ a_arr) {
  int tid = blockIdx.x * 256 + threadIdx.x;  // BT*16 threads
  int m = tid >> 4, h = tid & 15;
  float dw = 0.f, da = 0.f;
  const bf16* rw = t1 + (long)m * 192;
  const bf16* ra = rw + 64;
#pragma unroll
  for (int k8 = 0; k8 < 8; k8++) {
    bf16x8 aw = *(const bf16x8*)(rw + k8 * 8);
    bf16x8 aa = *(const bf16x8*)(ra + k8 * 8);
#pragma unroll
    for (int j = 0; j < 8; j++) {
      dw += (float)aw[j] * w2[(k8 * 8 + j) * 16 + h];
      da += (float)aa[j] * a2[(k8 * 8 + j) * 16 + h];
    }
  }
  // w = exp(-softplus(-(w0+dw)) - 0.5) = sigmoid(w0+dw) * exp(-0.5)
  w_arr[h * TBTOK + m] = 0.60653066f * sigmf(w0[h] + dw);
  a_arr[h * TBTOK + m] = sigmf(a0[h] + da);
}

// ---------------- scan pass1: fused prep + local chunk scan + cumprod -----------
// wave per (b,h,chunk). 128 bh * 32 chunks = 4096 waves.
__global__ __launch_bounds__(256) void scan1_kern(
    const bf16* __restrict__ k_buf, const bf16* __restrict__ v_buf, const bf16* __restrict__ r_buf,
    const float* __restrict__ k_k, const float* __restrict__ r_k,
    const float* __restrict__ a_arr, const float* __restrict__ w_arr,
    float* __restrict__ kv2, float* __restrict__ Parr, float* __restrict__ bonus) {
  int wid = blockIdx.x * 4 + (threadIdx.x >> 6);
  int lane = threadIdx.x & 63;
  int bh = wid >> 5, c = wid & 31;
  int b = bh >> 4, h = bh & 15;
  int mstart = b * TSEQ + c * CHUNK;
  int kc = h * 64 + lane;
  float kkc = k_k[kc], rkc = r_k[kc];
  float st = 0.f, cw = 1.f;
  long mbase = (long)mstart * CDIM + kc;
  int hm = h * TBTOK + mstart;
  long sbase = ((long)hm) * 64 + lane;
  // simple 1-deep software pipeline on the global loads
  float kf = (float)k_buf[mbase] * kkc;
  float vf = (float)v_buf[mbase];
  float rf = (float)r_buf[mbase];
  float af = a_arr[hm];
  float wt = w_arr[hm];
  for (int t = 0; t < CHUNK; t++) {
    float kf_n = 0.f, vf_n = 0.f, rf_n = 0.f, af_n = 0.f, wt_n = 0.f;
    if (t < CHUNK - 1) {
      kf_n = (float)k_buf[mbase + CDIM] * kkc;
      vf_n = (float)v_buf[mbase + CDIM];
      rf_n = (float)r_buf[mbase + CDIM];
      af_n = a_arr[hm + 1];
      wt_n = w_arr[hm + 1];
    }
    float ss = wredsum(kf * kf);
    float kkn = kf / fmaxf(sqrtf(ss), 1e-12f);
    st = st * wt + kkn * vf * af;
    kv2[sbase] = st;
    cw *= wt;
    float bs = wredsum(rf * kkn * rkc);
    if (lane == 0) {
      Parr[hm] = cw;
      bonus[(mstart + t) * HN + h] = bs;
    }
    kf = kf_n; vf = vf_n; rf = rf_n; af = af_n; wt = wt_n;
    mbase += CDIM; hm += 1; sbase += 64;
  }
}

// ---------------- scan pass2: serial carry scan over chunks ----------------
// carry[((h*8+b)*NCH + c)*64 + lane] = true state entering chunk c.
__global__ __launch_bounds__(64) void scan2_kern(const float* __restrict__ kv2,
                                                 const float* __restrict__ Parr,
                                                 float* __restrict__ carry) {
  int bh = blockIdx.x;  // 128: h = bh>>3, b = bh&7
  int h = bh >> 3, b = bh & 7;
  int lane = threadIdx.x;
  float S = 0.f;
  for (int c = 0; c < NCH; c++) {
    carry[(((h * 8 + b) * NCH) + c) * 64 + lane] = S;
    int mlast = b * TSEQ + c * CHUNK + (CHUNK - 1);
    float L = kv2[((long)(h * TBTOK + mlast)) * 64 + lane];
    float pw = Parr[h * TBTOK + mlast];
    S = L + pw * S;
  }
}

// ---------------- pass3: fixup + post (x_wkv*r + bonus*v, GroupNorm, *ln, *g) -----
__global__ __launch_bounds__(256) void post_kern(
    const float* __restrict__ kv2, const float* __restrict__ Parr,
    const float* __restrict__ carry,
    bf16* __restrict__ r_buf, const bf16* __restrict__ v_buf,
    const float* __restrict__ bonus, const bf16* __restrict__ g_buf,
    const float* __restrict__ ln_w, const float* __restrict__ ln_b) {
  int wid = blockIdx.x * 4 + (threadIdx.x >> 6);
  int lane = threadIdx.x & 63;
  int m = wid >> 4, h = wid & 15;
  int c = h * 64 + lane;
  int b = m >> 11, ch = (m & (TSEQ - 1)) >> 6;  // chunk of 64
  float st = kv2[((long)h * TBTOK + m) * 64 + lane] +
             Parr[h * TBTOK + m] * carry[((h * 8 + b) * NCH + ch) * 64 + lane];
  float rf = (float)r_buf[(long)m * CDIM + c];
  float vf = (float)v_buf[(long)m * CDIM + c];
  float bs = bonus[m * HN + h];
  float xw = st * rf + bs * vf;
  float mn = wredsum(xw) * (1.f / 64.f);
  float dv = xw - mn;
  float var = wredsum(dv * dv) * (1.f / 64.f);
  float xn = dv * rsqrtf(var + 1e-5f);
  float y = xn * ln_w[c] + ln_b[c];
  r_buf[(long)m * CDIM + c] = (bf16)(y * (float)g_buf[(long)m * CDIM + c]);
}

extern "C" void kernel_launch(void* const* d_in, const int* in_sizes, int n_in,
                              void* d_out, int out_size, void* d_ws, size_t ws_size,
                              hipStream_t stream) {
  const float* x    = (const float*)d_in[0];
  const float* x_r  = (const float*)d_in[1];
  const float* x_w  = (const float*)d_in[2];
  const float* x_k  = (const float*)d_in[3];
  const float* x_v  = (const float*)d_in[4];
  const float* x_a  = (const float*)d_in[5];
  const float* x_g  = (const float*)d_in[6];
  const float* w0   = (const float*)d_in[7];
  const float* w1   = (const float*)d_in[8];
  const float* w2   = (const float*)d_in[9];
  const float* a0   = (const float*)d_in[10];
  const float* a1   = (const float*)d_in[11];
  const float* a2   = (const float*)d_in[12];
  // v0,v1,v2 (13,14,15) unused: v_res_gate is a no-op in the reference
  const float* g1   = (const float*)d_in[16];
  const float* g2   = (const float*)d_in[17];
  const float* k_k  = (const float*)d_in[18];
  const float* r_k  = (const float*)d_in[19];
  const float* Wr   = (const float*)d_in[20];
  const float* Wk   = (const float*)d_in[21];
  const float* Wv   = (const float*)d_in[22];
  const float* Wo   = (const float*)d_in[23];
  const float* ln_w = (const float*)d_in[24];
  const float* ln_b = (const float*)d_in[25];
  float* out = (float*)d_out;

  // ---- carve workspace (~213 MB, with aliasing) ----
  char* p = (char*)d_ws;
  auto carve = [&](size_t bytes) {
    void* r = (void*)p;
    p += (bytes + 255) & ~(size_t)255;
    return r;
  };
  bf16* WrT = (bf16*)carve(1024 * 1024 * 2);
  bf16* WkT = (bf16*)carve(1024 * 1024 * 2);
  bf16* WvT = (bf16*)carve(1024 * 1024 * 2);
  bf16* WoT = (bf16*)carve(1024 * 1024 * 2);
  bf16* w1T = (bf16*)carve(64 * 1024 * 2);
  bf16* a1T = (bf16*)carve(64 * 1024 * 2);
  bf16* g1T = (bf16*)carve(64 * 1024 * 2);
  bf16* g2T = (bf16*)carve(1024 * 64 * 2);
  bf16* t1    = (bf16*)carve((size_t)TBTOK * 192 * 2);
  bf16* r_buf = (bf16*)carve((size_t)TBTOK * CDIM * 2);  // later reused as `an`
  bf16* k_buf = (bf16*)carve((size_t)TBTOK * CDIM * 2);
  bf16* v_buf = (bf16*)carve((size_t)TBTOK * CDIM * 2);
  float* w_arr = (float*)carve((size_t)TBTOK * HN * 4);
  float* a_arr = (float*)carve((size_t)TBTOK * HN * 4);
  float* bonus = (float*)carve((size_t)TBTOK * HN * 4);
  float* Parr  = (float*)carve((size_t)TBTOK * HN * 4);
  float* carry = (float*)carve((size_t)128 * NCH * 64 * 4);
  // shifted bf16 inputs; xr+xk region reused as kv2 (f32) after rkv GEMM,
  // xv region reused as g_buf (gate GEMM runs after rkv GEMM).
  bf16* xr = (bf16*)carve((size_t)TBTOK * CDIM * 2);  // 32MB
  bf16* xk = (bf16*)carve((size_t)TBTOK * CDIM * 2);  // 32MB (contiguous with xr)
  bf16* xv = (bf16*)carve((size_t)TBTOK * CDIM * 2);  // 32MB
  float* kv2  = (float*)xr;   // 64MB = xr+xk
  bf16*  g_buf = xv;          // 32MB

  dim3 tb(32, 8);
  transpose_cvt<<<dim3(32, 32), tb, 0, stream>>>(Wr, WrT, 1024, 1024);
  transpose_cvt<<<dim3(32, 32), tb, 0, stream>>>(Wk, WkT, 1024, 1024);
  transpose_cvt<<<dim3(32, 32), tb, 0, stream>>>(Wv, WvT, 1024, 1024);
  transpose_cvt<<<dim3(32, 32), tb, 0, stream>>>(Wo, WoT, 1024, 1024);
  transpose_cvt<<<dim3(2, 32), tb, 0, stream>>>(w1, w1T, 1024, 64);
  transpose_cvt<<<dim3(2, 32), tb, 0, stream>>>(a1, a1T, 1024, 64);
  transpose_cvt<<<dim3(2, 32), tb, 0, stream>>>(g1, g1T, 1024, 64);
  transpose_cvt<<<dim3(32, 2), tb, 0, stream>>>(g2, g2T, 64, 1024);

  // token-shift prepass (r,k,v) -> bf16
  mix3_kern<<<dim3(TBTOK * CDIM / 2048), 256, 0, stream>>>(x, x_r, x_k, x_v, xr, xk, xv);
  // LoRA stage1 (all 3 mats, x read once): t1 = tanh(shiftmix(x) @ {w1,a1,g1})
  gemm_stage1<<<dim3(TBTOK / 64), 256, 0, stream>>>(x, w1T, a1T, g1T, x_w, x_a, x_g, t1);
  // stage2 w,a
  stage2_wa<<<dim3(TBTOK * HN / 256), 256, 0, stream>>>(t1, w2, a2, w0, a0, w_arr, a_arr);
  // r,k,v projections (pure bf16, async staging)
  gemm128_kern<0, bf16><<<dim3(TBTOK / 128, 24), 256, 0, stream>>>(
      xr, xk, xv, CDIM, 0, WrT, WkT, WvT,
      r_buf, k_buf, v_buf, CDIM, 1024, 8);
  // gate: g = sigmoid(t1g @ g2)   (after rkv so g_buf can alias xv)
  gemm128_kern<1, bf16><<<dim3(TBTOK / 128, 8), 256, 0, stream>>>(
      t1, t1, t1, 192, 128, g2T, g2T, g2T,
      g_buf, g_buf, g_buf, CDIM, 64, 8);
  // chunked WKV scan: pass1 (prep+local scan), pass2 (carries), pass3 fused into post
  scan1_kern<<<dim3(128 * NCH / 4), 256, 0, stream>>>(
      k_buf, v_buf, r_buf, k_k, r_k, a_arr, w_arr, kv2, Parr, bonus);
  scan2_kern<<<dim3(128), 64, 0, stream>>>(kv2, Parr, carry);
  post_kern<<<dim3(TBTOK * HN / 4), 256, 0, stream>>>(
      kv2, Parr, carry, r_buf, v_buf, bonus, g_buf, ln_w, ln_b);
  // out = an @ Wo  (f32 output)
  gemm128_kern<0, float><<<dim3(TBTOK / 128, 8), 256, 0, stream>>>(
      r_buf, r_buf, r_buf, CDIM, 0, WoT, WoT, WoT,
      out, out, out, CDIM, 1024, 8);
}

// Round 5
// 592.009 us; speedup vs baseline: 1.2013x; 1.0877x over previous
//
#include <hip/hip_runtime.h>

// RWKV v7 TimeMix forward, MI355X gfx950.
// B=8 T=2048 C=1024 H=16 D=64 DLOW=64. I/O f32, internal bf16 MFMA + f32 scan.
// R5: diag-trick LoRA stage1 (K=2048, pre-scaled weights), fused transpose_all,
//     gate GEMM absorbs groupnorm/post epilogue, 9 launches total.

typedef __bf16 bf16;
typedef __attribute__((ext_vector_type(8))) __bf16 bf16x8;
typedef __attribute__((ext_vector_type(4))) float f32x4;

#define TBTOK 16384   // B*T
#define TSEQ  2048
#define CDIM  1024
#define HN    16
#define CHUNK 64
#define NCH   32      // TSEQ / CHUNK

__device__ __forceinline__ float wredsum(float v) {
#pragma unroll
  for (int o = 32; o > 0; o >>= 1) v += __shfl_xor(v, o, 64);
  return v;
}
__device__ __forceinline__ float qredsum(float v) {  // reduce over 16-lane quad group
#pragma unroll
  for (int o = 8; o > 0; o >>= 1) v += __shfl_xor(v, o, 64);
  return v;
}
__device__ __forceinline__ float sigmf(float x) { return 1.f / (1.f + expf(-x)); }

// async global->LDS, 16 bytes/lane. LDS base wave-uniform (HW adds lane*16).
__device__ __forceinline__ void gl_lds16(const bf16* g, bf16* l) {
  __builtin_amdgcn_global_load_lds(
      (const __attribute__((address_space(1))) unsigned int*)g,
      (__attribute__((address_space(3))) unsigned int*)l, 16, 0, 0);
}

// ---------------- transpose_all: every weight prep in one launch ----------------
// blocks 0..4095            : WrT/WkT/WvT/WoT  (1024x1024 f32 -> [n][k] bf16)
// blocks 4096..4479         : Bcat[192][2048]  (w1/a1/g1 scaled by diag trick)
// blocks 4480..4543         : g2T[1024][64]
// block  4544               : w2T/a2T [16][64] + zpad zeros
__global__ __launch_bounds__(256) void transpose_all(
    const float* __restrict__ Wr, const float* __restrict__ Wk,
    const float* __restrict__ Wv, const float* __restrict__ Wo,
    const float* __restrict__ w1, const float* __restrict__ a1, const float* __restrict__ g1,
    const float* __restrict__ mw, const float* __restrict__ ma, const float* __restrict__ mg,
    const float* __restrict__ g2, const float* __restrict__ w2, const float* __restrict__ a2,
    bf16* __restrict__ WrT, bf16* __restrict__ WkT, bf16* __restrict__ WvT, bf16* __restrict__ WoT,
    bf16* __restrict__ Bcat, bf16* __restrict__ g2T,
    bf16* __restrict__ w2T, bf16* __restrict__ a2T, float* __restrict__ zpad) {
  int bid = blockIdx.x;
  int tid = threadIdx.x;
  int tx = tid & 31, ty = tid >> 5;  // 32 x 8
  __shared__ bf16 tile[32][33];

  if (bid < 4096) {
    int sel = bid >> 10, t = bid & 1023;
    int k0 = (t >> 5) * 32, n0 = (t & 31) * 32;
    const float* src = sel == 0 ? Wr : (sel == 1 ? Wk : (sel == 2 ? Wv : Wo));
    bf16* dst = sel == 0 ? WrT : (sel == 1 ? WkT : (sel == 2 ? WvT : WoT));
#pragma unroll
    for (int i = 0; i < 4; i++)
      tile[ty + i * 8][tx] = (bf16)src[(long)(k0 + ty + i * 8) * 1024 + n0 + tx];
    __syncthreads();
#pragma unroll
    for (int i = 0; i < 4; i++)
      dst[(long)(n0 + ty + i * 8) * 1024 + k0 + tx] = tile[tx][ty + i * 8];
  } else if (bid < 4480) {
    int idx = bid - 4096;
    int mat = idx >> 7, rem = idx & 127;
    int half = rem >> 6, t = rem & 63;
    int k0 = (t >> 1) * 32, n0 = (t & 1) * 32;
    const float* W = mat == 0 ? w1 : (mat == 1 ? a1 : g1);
    const float* mx = mat == 0 ? mw : (mat == 1 ? ma : mg);
#pragma unroll
    for (int i = 0; i < 4; i++) {
      int k = k0 + ty + i * 8;
      float s = half == 0 ? (1.f + mx[k]) : (-mx[k]);
      tile[ty + i * 8][tx] = (bf16)(s * W[(long)k * 64 + n0 + tx]);
    }
    __syncthreads();
#pragma unroll
    for (int i = 0; i < 4; i++)
      Bcat[(long)(mat * 64 + n0 + ty + i * 8) * 2048 + half * 1024 + k0 + tx] =
          tile[tx][ty + i * 8];
  } else if (bid < 4544) {
    int t = bid - 4480;
    int k0 = (t >> 5) * 32, n0 = (t & 31) * 32;
#pragma unroll
    for (int i = 0; i < 4; i++)
      tile[ty + i * 8][tx] = (bf16)g2[(long)(k0 + ty + i * 8) * 1024 + n0 + tx];
    __syncthreads();
#pragma unroll
    for (int i = 0; i < 4; i++)
      g2T[(long)(n0 + ty + i * 8) * 64 + k0 + tx] = tile[tx][ty + i * 8];
  } else {
#pragma unroll
    for (int rep = 0; rep < 4; rep++) {
      int idx = rep * 256 + tid;  // 0..1023
      int k = idx >> 4, h = idx & 15;
      w2T[h * 64 + k] = (bf16)w2[idx];
      a2T[h * 64 + k] = (bf16)a2[idx];
    }
    if (tid < 64) zpad[tid] = 0.f;
  }
}

// ---------------- mixcvt: token-shift mix r,k,v + plain bf16 cast of x ----------
__global__ __launch_bounds__(256) void mixcvt_kern(
    const float* __restrict__ x, const float* __restrict__ mr,
    const float* __restrict__ mk, const float* __restrict__ mv,
    bf16* __restrict__ xr, bf16* __restrict__ xk, bf16* __restrict__ xv,
    bf16* __restrict__ xbf) {
  long i8 = ((long)blockIdx.x * 256 + threadIdx.x) * 8;
  int m = (int)(i8 >> 10);
  int c = (int)(i8 & 1023);
  f32x4 x0 = *(const f32x4*)(x + i8);
  f32x4 x1 = *(const f32x4*)(x + i8 + 4);
  f32x4 p0 = {0.f, 0.f, 0.f, 0.f}, p1 = {0.f, 0.f, 0.f, 0.f};
  if ((m & (TSEQ - 1)) != 0) {
    p0 = *(const f32x4*)(x + i8 - CDIM);
    p1 = *(const f32x4*)(x + i8 - CDIM + 4);
  }
  f32x4 r0 = *(const f32x4*)(mr + c), r1 = *(const f32x4*)(mr + c + 4);
  f32x4 k0 = *(const f32x4*)(mk + c), k1 = *(const f32x4*)(mk + c + 4);
  f32x4 v0 = *(const f32x4*)(mv + c), v1 = *(const f32x4*)(mv + c + 4);
  bf16x8 or_, ok_, ov_, ox_;
#pragma unroll
  for (int j = 0; j < 4; j++) {
    float s0 = x0[j] - p0[j], s1 = x1[j] - p1[j];
    or_[j] = (bf16)(x0[j] + s0 * r0[j]); or_[4 + j] = (bf16)(x1[j] + s1 * r1[j]);
    ok_[j] = (bf16)(x0[j] + s0 * k0[j]); ok_[4 + j] = (bf16)(x1[j] + s1 * k1[j]);
    ov_[j] = (bf16)(x0[j] + s0 * v0[j]); ov_[4 + j] = (bf16)(x1[j] + s1 * v1[j]);
    ox_[j] = (bf16)x0[j];                ox_[4 + j] = (bf16)x1[j];
  }
  *(bf16x8*)(xr + i8) = or_;
  *(bf16x8*)(xk + i8) = ok_;
  *(bf16x8*)(xv + i8) = ov_;
  *(bf16x8*)(xbf + i8) = ox_;
}

// ---------------- m97-style GEMM: 128x128 tile, BK=32, global_load_lds staging ----------
template <int ACT, typename OT>   // ACT: 0 none, 1 sigmoid
__global__ __launch_bounds__(256) void gemm128_kern(
    const bf16* __restrict__ A0, const bf16* __restrict__ A1, const bf16* __restrict__ A2,
    int apitch, int acol0,
    const bf16* __restrict__ BT0, const bf16* __restrict__ BT1, const bf16* __restrict__ BT2,
    OT* __restrict__ out0, OT* __restrict__ out1, OT* __restrict__ out2,
    int opitch, int K, int nbpm) {
  int by = blockIdx.y;
  int mat = by / nbpm;
  int ncol0 = (by % nbpm) * 128;
  const bf16* Am = mat == 0 ? A0 : (mat == 1 ? A1 : A2);
  const bf16* BTm = mat == 0 ? BT0 : (mat == 1 ? BT1 : BT2);
  OT* out = mat == 0 ? out0 : (mat == 1 ? out1 : out2);
  int m0 = blockIdx.x * 128;

  __shared__ bf16 Al[128 * 32];  // unpadded: required by global_load_lds lane order
  __shared__ bf16 Bl[128 * 32];

  int tid = threadIdx.x;
  int w = tid >> 6, lane = tid & 63, quad = lane >> 4, lr = lane & 15;
  int wm = (w & 1) * 64, wn = (w >> 1) * 64;

  f32x4 acc[4][4] = {};

  int r0 = tid >> 2, kc0 = (tid & 3) * 8;
  const bf16* ag0 = Am + (long)(m0 + r0) * apitch + acol0 + kc0;
  const bf16* ag1 = ag0 + (long)64 * apitch;
  const bf16* bg0 = BTm + (long)(ncol0 + r0) * K + kc0;
  const bf16* bg1 = bg0 + (long)64 * K;
  bf16* la0 = Al + w * 512;
  bf16* la1 = Al + 2048 + w * 512;
  bf16* lb0 = Bl + w * 512;
  bf16* lb1 = Bl + 2048 + w * 512;

  for (int k0 = 0; k0 < K; k0 += 32) {
    gl_lds16(ag0, la0);
    gl_lds16(ag1, la1);
    gl_lds16(bg0, lb0);
    gl_lds16(bg1, lb1);
    ag0 += 32; ag1 += 32; bg0 += 32; bg1 += 32;
    __syncthreads();
    bf16x8 af[4], bff[4];
#pragma unroll
    for (int i = 0; i < 4; i++) af[i] = *(const bf16x8*)&Al[(wm + i * 16 + lr) * 32 + quad * 8];
#pragma unroll
    for (int j = 0; j < 4; j++) bff[j] = *(const bf16x8*)&Bl[(wn + j * 16 + lr) * 32 + quad * 8];
#pragma unroll
    for (int i = 0; i < 4; i++)
#pragma unroll
      for (int j = 0; j < 4; j++)
        acc[i][j] = __builtin_amdgcn_mfma_f32_16x16x32_bf16(af[i], bff[j], acc[i][j], 0, 0, 0);
    __syncthreads();
  }
#pragma unroll
  for (int i = 0; i < 4; i++)
#pragma unroll
    for (int j = 0; j < 4; j++)
#pragma unroll
      for (int rg = 0; rg < 4; rg++) {
        int row = m0 + wm + i * 16 + quad * 4 + rg;
        int col = ncol0 + wn + j * 16 + lr;
        float v = acc[i][j][rg];
        if (ACT == 1) v = sigmf(v);
        out[(long)row * opitch + col] = (OT)v;
      }
}

// ---------------- stage1_diag: t1 = tanh([x|xprev] @ Bcat^T), K=2048, N=192 --------
// 64-row blocks, 4 waves x (16 rows x 192 cols).
__global__ __launch_bounds__(256) void stage1_diag(
    const bf16* __restrict__ xbf, const bf16* __restrict__ Bcat,
    const float* __restrict__ zpad, bf16* __restrict__ t1) {
  int m0 = blockIdx.x * 64;
  __shared__ bf16 Al[64 * 32];    // 4 KB
  __shared__ bf16 Bl[192 * 32];   // 12 KB

  int tid = threadIdx.x;
  int w = tid >> 6, lane = tid & 63, quad = lane >> 4, lr = lane & 15;
  int wm = w * 16;

  f32x4 acc[12] = {};

  int r0 = tid >> 2, kc0 = (tid & 3) * 8;
  int m = m0 + r0;
  // A sources: pass 1 = x rows, pass 2 = xprev rows (zero at sequence start)
  const bf16* asrc = xbf + (long)m * CDIM + kc0;
  bool firstrow = (m & (TSEQ - 1)) == 0;
  const bf16* psrc = firstrow ? (const bf16*)zpad : xbf + (long)(m - 1) * CDIM + kc0;
  int pstep = firstrow ? 0 : 32;
  // B sources: 3 chunks of 64 rows
  const bf16* bs0 = Bcat + (long)(r0)       * 2048 + kc0;
  const bf16* bs1 = Bcat + (long)(r0 + 64)  * 2048 + kc0;
  const bf16* bs2 = Bcat + (long)(r0 + 128) * 2048 + kc0;
  bf16* la = Al + w * 512;
  bf16* lb0 = Bl + w * 512;
  bf16* lb1 = Bl + 2048 + w * 512;
  bf16* lb2 = Bl + 4096 + w * 512;

#pragma unroll 1
  for (int kk = 0; kk < 64; kk++) {
    if (kk < 32) {
      gl_lds16(asrc, la);
      asrc += 32;
    } else {
      gl_lds16(psrc, la);
      psrc += pstep;
    }
    gl_lds16(bs0, lb0);
    gl_lds16(bs1, lb1);
    gl_lds16(bs2, lb2);
    bs0 += 32; bs1 += 32; bs2 += 32;
    __syncthreads();
    bf16x8 af = *(const bf16x8*)&Al[(wm + lr) * 32 + quad * 8];
#pragma unroll
    for (int nf = 0; nf < 12; nf++) {
      bf16x8 bff = *(const bf16x8*)&Bl[(nf * 16 + lr) * 32 + quad * 8];
      acc[nf] = __builtin_amdgcn_mfma_f32_16x16x32_bf16(af, bff, acc[nf], 0, 0, 0);
    }
    __syncthreads();
  }
#pragma unroll
  for (int nf = 0; nf < 12; nf++)
#pragma unroll
    for (int rg = 0; rg < 4; rg++) {
      int row = m0 + wm + quad * 4 + rg;
      int col = nf * 16 + lr;
      t1[(long)row * 192 + col] = (bf16)tanhf(acc[nf][rg]);
    }
}

// ---------------- stage2 w/a: tiny K=64,N=16 dots (bf16 weights) ----------------
__global__ __launch_bounds__(256) void stage2_wa(
    const bf16* __restrict__ t1, const bf16* __restrict__ w2T, const bf16* __restrict__ a2T,
    const float* __restrict__ w0, const float* __restrict__ a0,
    float* __restrict__ w_arr, float* __restrict__ a_arr) {
  int tid = blockIdx.x * 256 + threadIdx.x;  // BT*16 threads
  int m = tid >> 4, h = tid & 15;
  float dw = 0.f, da = 0.f;
  const bf16* rw = t1 + (long)m * 192;
  const bf16* ra = rw + 64;
  const bf16* ww = w2T + h * 64;
  const bf16* aw = a2T + h * 64;
#pragma unroll
  for (int k8 = 0; k8 < 8; k8++) {
    bf16x8 tw = *(const bf16x8*)(rw + k8 * 8);
    bf16x8 ta = *(const bf16x8*)(ra + k8 * 8);
    bf16x8 cw = *(const bf16x8*)(ww + k8 * 8);
    bf16x8 ca = *(const bf16x8*)(aw + k8 * 8);
#pragma unroll
    for (int j = 0; j < 8; j++) {
      dw += (float)tw[j] * (float)cw[j];
      da += (float)ta[j] * (float)ca[j];
    }
  }
  // w = exp(-softplus(-(w0+dw)) - 0.5) = sigmoid(w0+dw) * exp(-0.5)
  w_arr[h * TBTOK + m] = 0.60653066f * sigmf(w0[h] + dw);
  a_arr[h * TBTOK + m] = sigmf(a0[h] + da);
}

// ---------------- scan pass1: fused prep + local chunk scan + cumprod -----------
__global__ __launch_bounds__(256) void scan1_kern(
    const bf16* __restrict__ k_buf, const bf16* __restrict__ v_buf, const bf16* __restrict__ r_buf,
    const float* __restrict__ k_k, const float* __restrict__ r_k,
    const float* __restrict__ a_arr, const float* __restrict__ w_arr,
    float* __restrict__ kv2, float* __restrict__ Parr, float* __restrict__ bonus) {
  int wid = blockIdx.x * 4 + (threadIdx.x >> 6);
  int lane = threadIdx.x & 63;
  int bh = wid >> 5, c = wid & 31;
  int b = bh >> 4, h = bh & 15;
  int mstart = b * TSEQ + c * CHUNK;
  int kc = h * 64 + lane;
  float kkc = k_k[kc], rkc = r_k[kc];
  float st = 0.f, cw = 1.f;
  long mbase = (long)mstart * CDIM + kc;
  int hm = h * TBTOK + mstart;
  long sbase = ((long)hm) * 64 + lane;
  float kf = (float)k_buf[mbase] * kkc;
  float vf = (float)v_buf[mbase];
  float rf = (float)r_buf[mbase];
  float af = a_arr[hm];
  float wt = w_arr[hm];
  for (int t = 0; t < CHUNK; t++) {
    float kf_n = 0.f, vf_n = 0.f, rf_n = 0.f, af_n = 0.f, wt_n = 0.f;
    if (t < CHUNK - 1) {
      kf_n = (float)k_buf[mbase + CDIM] * kkc;
      vf_n = (float)v_buf[mbase + CDIM];
      rf_n = (float)r_buf[mbase + CDIM];
      af_n = a_arr[hm + 1];
      wt_n = w_arr[hm + 1];
    }
    float ss = wredsum(kf * kf);
    float kkn = kf / fmaxf(sqrtf(ss), 1e-12f);
    st = st * wt + kkn * vf * af;
    kv2[sbase] = st;
    cw *= wt;
    float bs = wredsum(rf * kkn * rkc);
    if (lane == 0) {
      Parr[hm] = cw;
      bonus[(mstart + t) * HN + h] = bs;
    }
    kf = kf_n; vf = vf_n; rf = rf_n; af = af_n; wt = wt_n;
    mbase += CDIM; hm += 1; sbase += 64;
  }
}

// ---------------- scan pass2: serial carry scan over chunks ----------------
__global__ __launch_bounds__(64) void scan2_kern(const float* __restrict__ kv2,
                                                 const float* __restrict__ Parr,
                                                 float* __restrict__ carry) {
  int bh = blockIdx.x;  // 128: h = bh>>3, b = bh&7
  int h = bh >> 3, b = bh & 7;
  int lane = threadIdx.x;
  float S = 0.f;
  for (int c = 0; c < NCH; c++) {
    carry[(((h * 8 + b) * NCH) + c) * 64 + lane] = S;
    int mlast = b * TSEQ + c * CHUNK + (CHUNK - 1);
    float L = kv2[((long)(h * TBTOK + mlast)) * 64 + lane];
    float pw = Parr[h * TBTOK + mlast];
    S = L + pw * S;
  }
}

// ---------------- gate_post: g = sigmoid(t1g @ g2), fused WKV fixup + groupnorm ----
// 128x128 tile (2 heads wide), K=64. Epilogue does the whole "post" computation.
__global__ __launch_bounds__(256) void gate_post_kern(
    const bf16* __restrict__ t1, const bf16* __restrict__ g2T,
    const float* __restrict__ kv2, const float* __restrict__ Parr,
    const float* __restrict__ carry, const float* __restrict__ bonus,
    bf16* __restrict__ r_buf, const bf16* __restrict__ v_buf,
    const float* __restrict__ ln_w, const float* __restrict__ ln_b) {
  int ncol0 = blockIdx.y * 128;
  int m0 = blockIdx.x * 128;

  __shared__ bf16 Al[128 * 32];
  __shared__ bf16 Bl[128 * 32];

  int tid = threadIdx.x;
  int w = tid >> 6, lane = tid & 63, quad = lane >> 4, lr = lane & 15;
  int wm = (w & 1) * 64, wn = (w >> 1) * 64;

  f32x4 acc[4][4] = {};

  int r0 = tid >> 2, kc0 = (tid & 3) * 8;
  const bf16* ag0 = t1 + (long)(m0 + r0) * 192 + 128 + kc0;
  const bf16* ag1 = ag0 + (long)64 * 192;
  const bf16* bg0 = g2T + (long)(ncol0 + r0) * 64 + kc0;
  const bf16* bg1 = bg0 + (long)64 * 64;
  bf16* la0 = Al + w * 512;
  bf16* la1 = Al + 2048 + w * 512;
  bf16* lb0 = Bl + w * 512;
  bf16* lb1 = Bl + 2048 + w * 512;

  for (int k0 = 0; k0 < 64; k0 += 32) {
    gl_lds16(ag0, la0);
    gl_lds16(ag1, la1);
    gl_lds16(bg0, lb0);
    gl_lds16(bg1, lb1);
    ag0 += 32; ag1 += 32; bg0 += 32; bg1 += 32;
    __syncthreads();
    bf16x8 af[4], bff[4];
#pragma unroll
    for (int i = 0; i < 4; i++) af[i] = *(const bf16x8*)&Al[(wm + i * 16 + lr) * 32 + quad * 8];
#pragma unroll
    for (int j = 0; j < 4; j++) bff[j] = *(const bf16x8*)&Bl[(wn + j * 16 + lr) * 32 + quad * 8];
#pragma unroll
    for (int i = 0; i < 4; i++)
#pragma unroll
      for (int j = 0; j < 4; j++)
        acc[i][j] = __builtin_amdgcn_mfma_f32_16x16x32_bf16(af[i], bff[j], acc[i][j], 0, 0, 0);
    __syncthreads();
  }

  // ---- epilogue: wkv fixup + r*st + bonus*v, groupnorm over 64-col head, *ln, *g ----
  int col0 = ncol0 + wn;        // multiple of 64 -> head
  int h = col0 >> 6;
  int b = m0 >> 11;                          // wave rows all in same sequence block
  int ch = ((m0 + wm) & (TSEQ - 1)) >> 6;    // wave rows all in same chunk
  float cy[4], lnwv[4], lnbv[4];
#pragma unroll
  for (int j = 0; j < 4; j++) {
    int d = j * 16 + lr;
    cy[j] = carry[((h * 8 + b) * NCH + ch) * 64 + d];
    lnwv[j] = ln_w[col0 + d];
    lnbv[j] = ln_b[col0 + d];
  }
#pragma unroll
  for (int i = 0; i < 4; i++)
#pragma unroll
    for (int rg = 0; rg < 4; rg++) {
      int row = m0 + wm + i * 16 + quad * 4 + rg;
      float pw = Parr[h * TBTOK + row];
      float bs = bonus[row * HN + h];
      long kvb = ((long)h * TBTOK + row) * 64;
      long rb = (long)row * CDIM + col0;
      float xw[4];
#pragma unroll
      for (int j = 0; j < 4; j++) {
        int d = j * 16 + lr;
        float st = kv2[kvb + d] + pw * cy[j];
        float rf = (float)r_buf[rb + d];
        float vf = (float)v_buf[rb + d];
        xw[j] = st * rf + bs * vf;
      }
      float sum = xw[0] + xw[1] + xw[2] + xw[3];
      float mn = qredsum(sum) * (1.f / 64.f);
      float vs = 0.f;
#pragma unroll
      for (int j = 0; j < 4; j++) {
        xw[j] -= mn;
        vs += xw[j] * xw[j];
      }
      float var = qredsum(vs) * (1.f / 64.f);
      float rq = rsqrtf(var + 1e-5f);
#pragma unroll
      for (int j = 0; j < 4; j++) {
        int d = j * 16 + lr;
        float y = xw[j] * rq * lnwv[j] + lnbv[j];
        float gv = sigmf(acc[i][j][rg]);
        r_buf[rb + d] = (bf16)(y * gv);
      }
    }
}

extern "C" void kernel_launch(void* const* d_in, const int* in_sizes, int n_in,
                              void* d_out, int out_size, void* d_ws, size_t ws_size,
                              hipStream_t stream) {
  const float* x    = (const float*)d_in[0];
  const float* x_r  = (const float*)d_in[1];
  const float* x_w  = (const float*)d_in[2];
  const float* x_k  = (const float*)d_in[3];
  const float* x_v  = (const float*)d_in[4];
  const float* x_a  = (const float*)d_in[5];
  const float* x_g  = (const float*)d_in[6];
  const float* w0   = (const float*)d_in[7];
  const float* w1   = (const float*)d_in[8];
  const float* w2   = (const float*)d_in[9];
  const float* a0   = (const float*)d_in[10];
  const float* a1   = (const float*)d_in[11];
  const float* a2   = (const float*)d_in[12];
  // v0,v1,v2 (13,14,15) unused: v_res_gate is a no-op in the reference
  const float* g1   = (const float*)d_in[16];
  const float* g2   = (const float*)d_in[17];
  const float* k_k  = (const float*)d_in[18];
  const float* r_k  = (const float*)d_in[19];
  const float* Wr   = (const float*)d_in[20];
  const float* Wk   = (const float*)d_in[21];
  const float* Wv   = (const float*)d_in[22];
  const float* Wo   = (const float*)d_in[23];
  const float* ln_w = (const float*)d_in[24];
  const float* ln_b = (const float*)d_in[25];
  float* out = (float*)d_out;

  // ---- carve workspace (~211 MB, with aliasing) ----
  char* p = (char*)d_ws;
  auto carve = [&](size_t bytes) {
    void* r = (void*)p;
    p += (bytes + 255) & ~(size_t)255;
    return r;
  };
  bf16* WrT = (bf16*)carve(1024 * 1024 * 2);
  bf16* WkT = (bf16*)carve(1024 * 1024 * 2);
  bf16* WvT = (bf16*)carve(1024 * 1024 * 2);
  bf16* WoT = (bf16*)carve(1024 * 1024 * 2);
  bf16* Bcat = (bf16*)carve(192 * 2048 * 2);
  bf16* g2T  = (bf16*)carve(1024 * 64 * 2);
  bf16* w2T  = (bf16*)carve(16 * 64 * 2);
  bf16* a2T  = (bf16*)carve(16 * 64 * 2);
  float* zpad = (float*)carve(64 * 4);
  bf16* t1    = (bf16*)carve((size_t)TBTOK * 192 * 2);
  bf16* r_buf = (bf16*)carve((size_t)TBTOK * CDIM * 2);  // later holds `an`
  bf16* k_buf = (bf16*)carve((size_t)TBTOK * CDIM * 2);
  bf16* v_buf = (bf16*)carve((size_t)TBTOK * CDIM * 2);
  float* w_arr = (float*)carve((size_t)TBTOK * HN * 4);
  float* a_arr = (float*)carve((size_t)TBTOK * HN * 4);
  float* bonus = (float*)carve((size_t)TBTOK * HN * 4);
  float* Parr  = (float*)carve((size_t)TBTOK * HN * 4);
  float* carry = (float*)carve((size_t)128 * NCH * 64 * 4);
  bf16* xr  = (bf16*)carve((size_t)TBTOK * CDIM * 2);  // 32MB
  bf16* xk  = (bf16*)carve((size_t)TBTOK * CDIM * 2);  // 32MB
  bf16* xv  = (bf16*)carve((size_t)TBTOK * CDIM * 2);  // 32MB
  bf16* xbf = (bf16*)carve((size_t)TBTOK * CDIM * 2);  // 32MB (contiguous after xv)
  float* kv2 = (float*)xv;  // 64MB = xv+xbf, both dead before scan1

  // 1. all weight prep in one launch
  transpose_all<<<dim3(4545), 256, 0, stream>>>(
      Wr, Wk, Wv, Wo, w1, a1, g1, x_w, x_a, x_g, g2, w2, a2,
      WrT, WkT, WvT, WoT, Bcat, g2T, w2T, a2T, zpad);
  // 2. token-shift mixes + bf16 cast of x
  mixcvt_kern<<<dim3(TBTOK * CDIM / 2048), 256, 0, stream>>>(
      x, x_r, x_k, x_v, xr, xk, xv, xbf);
  // 3. LoRA stage1 via diag trick: t1 = tanh([x|xprev] @ Bcat^T)
  stage1_diag<<<dim3(TBTOK / 64), 256, 0, stream>>>(xbf, Bcat, zpad, t1);
  // 4. stage2 w,a
  stage2_wa<<<dim3(TBTOK * HN / 256), 256, 0, stream>>>(t1, w2T, a2T, w0, a0, w_arr, a_arr);
  // 5. r,k,v projections
  gemm128_kern<0, bf16><<<dim3(TBTOK / 128, 24), 256, 0, stream>>>(
      xr, xk, xv, CDIM, 0, WrT, WkT, WvT,
      r_buf, k_buf, v_buf, CDIM, 1024, 8);
  // 6-7. chunked WKV scan
  scan1_kern<<<dim3(128 * NCH / 4), 256, 0, stream>>>(
      k_buf, v_buf, r_buf, k_k, r_k, a_arr, w_arr, kv2, Parr, bonus);
  scan2_kern<<<dim3(128), 64, 0, stream>>>(kv2, Parr, carry);
  // 8. gate GEMM + fused fixup/groupnorm/gating -> an (into r_buf)
  gate_post_kern<<<dim3(TBTOK / 128, 8), 256, 0, stream>>>(
      t1, g2T, kv2, Parr, carry, bonus, r_buf, v_buf, ln_w, ln_b);
  // 9. out = an @ Wo  (f32 output)
  gemm128_kern<0, float><<<dim3(TBTOK / 128, 8), 256, 0, stream>>>(
      r_buf, r_buf, r_buf, CDIM, 0, WoT, WoT, WoT,
      out, out, out, CDIM, 1024, 8);
}

// Round 6
// 583.944 us; speedup vs baseline: 1.2179x; 1.0138x over previous
//
#include <hip/hip_runtime.h>

// RWKV v7 TimeMix forward, MI355X gfx950.
// B=8 T=2048 C=1024 H=16 D=64 DLOW=64. I/O f32, internal bf16 MFMA + f32 scan.
// R6: BK=64 + XOR-swizzled LDS in big GEMMs (kills 8-way bank conflicts, halves
//     barriers), stage2 fused into stage1, prep kernels merged. 7 launches.

typedef __bf16 bf16;
typedef __attribute__((ext_vector_type(8))) __bf16 bf16x8;
typedef __attribute__((ext_vector_type(4))) float f32x4;

#define TBTOK 16384   // B*T
#define TSEQ  2048
#define CDIM  1024
#define HN    16
#define CHUNK 64
#define NCH   32      // TSEQ / CHUNK

__device__ __forceinline__ float wredsum(float v) {
#pragma unroll
  for (int o = 32; o > 0; o >>= 1) v += __shfl_xor(v, o, 64);
  return v;
}
__device__ __forceinline__ float qredsum(float v) {  // reduce over the 16-lane group
#pragma unroll
  for (int o = 8; o > 0; o >>= 1) v += __shfl_xor(v, o, 64);
  return v;
}
__device__ __forceinline__ float sigmf(float x) { return 1.f / (1.f + expf(-x)); }

// async global->LDS, 16 bytes/lane. LDS base wave-uniform (HW adds lane*16).
__device__ __forceinline__ void gl_lds16(const bf16* g, bf16* l) {
  __builtin_amdgcn_global_load_lds(
      (const __attribute__((address_space(1))) unsigned int*)g,
      (__attribute__((address_space(3))) unsigned int*)l, 16, 0, 0);
}

// ---------------- prep: mixcvt (blocks 0..8191) + all weight transposes ----------
__global__ __launch_bounds__(256) void prep_kern(
    const float* __restrict__ x, const float* __restrict__ mr,
    const float* __restrict__ mk, const float* __restrict__ mv,
    bf16* __restrict__ xr, bf16* __restrict__ xk, bf16* __restrict__ xv,
    bf16* __restrict__ xbf,
    const float* __restrict__ Wr, const float* __restrict__ Wk,
    const float* __restrict__ Wv, const float* __restrict__ Wo,
    const float* __restrict__ w1, const float* __restrict__ a1, const float* __restrict__ g1,
    const float* __restrict__ mw, const float* __restrict__ ma, const float* __restrict__ mg,
    const float* __restrict__ g2, const float* __restrict__ w2, const float* __restrict__ a2,
    bf16* __restrict__ WrT, bf16* __restrict__ WkT, bf16* __restrict__ WvT, bf16* __restrict__ WoT,
    bf16* __restrict__ Bcat, bf16* __restrict__ g2T,
    bf16* __restrict__ w2T, bf16* __restrict__ a2T, float* __restrict__ zpad) {
  int bid0 = blockIdx.x;
  int tid = threadIdx.x;
  if (bid0 < 8192) {
    long i8 = ((long)bid0 * 256 + tid) * 8;
    int m = (int)(i8 >> 10);
    int c = (int)(i8 & 1023);
    f32x4 x0 = *(const f32x4*)(x + i8);
    f32x4 x1 = *(const f32x4*)(x + i8 + 4);
    f32x4 p0 = {0.f, 0.f, 0.f, 0.f}, p1 = {0.f, 0.f, 0.f, 0.f};
    if ((m & (TSEQ - 1)) != 0) {
      p0 = *(const f32x4*)(x + i8 - CDIM);
      p1 = *(const f32x4*)(x + i8 - CDIM + 4);
    }
    f32x4 r0 = *(const f32x4*)(mr + c), r1 = *(const f32x4*)(mr + c + 4);
    f32x4 k0 = *(const f32x4*)(mk + c), k1 = *(const f32x4*)(mk + c + 4);
    f32x4 v0 = *(const f32x4*)(mv + c), v1 = *(const f32x4*)(mv + c + 4);
    bf16x8 or_, ok_, ov_, ox_;
#pragma unroll
    for (int j = 0; j < 4; j++) {
      float s0 = x0[j] - p0[j], s1 = x1[j] - p1[j];
      or_[j] = (bf16)(x0[j] + s0 * r0[j]); or_[4 + j] = (bf16)(x1[j] + s1 * r1[j]);
      ok_[j] = (bf16)(x0[j] + s0 * k0[j]); ok_[4 + j] = (bf16)(x1[j] + s1 * k1[j]);
      ov_[j] = (bf16)(x0[j] + s0 * v0[j]); ov_[4 + j] = (bf16)(x1[j] + s1 * v1[j]);
      ox_[j] = (bf16)x0[j];                ox_[4 + j] = (bf16)x1[j];
    }
    *(bf16x8*)(xr + i8) = or_;
    *(bf16x8*)(xk + i8) = ok_;
    *(bf16x8*)(xv + i8) = ov_;
    *(bf16x8*)(xbf + i8) = ox_;
    return;
  }
  int bid = bid0 - 8192;
  int tx = tid & 31, ty = tid >> 5;  // 32 x 8
  __shared__ bf16 tile[32][33];
  if (bid < 4096) {
    int sel = bid >> 10, t = bid & 1023;
    int k0 = (t >> 5) * 32, n0 = (t & 31) * 32;
    const float* src = sel == 0 ? Wr : (sel == 1 ? Wk : (sel == 2 ? Wv : Wo));
    bf16* dst = sel == 0 ? WrT : (sel == 1 ? WkT : (sel == 2 ? WvT : WoT));
#pragma unroll
    for (int i = 0; i < 4; i++)
      tile[ty + i * 8][tx] = (bf16)src[(long)(k0 + ty + i * 8) * 1024 + n0 + tx];
    __syncthreads();
#pragma unroll
    for (int i = 0; i < 4; i++)
      dst[(long)(n0 + ty + i * 8) * 1024 + k0 + tx] = tile[tx][ty + i * 8];
  } else if (bid < 4480) {
    int idx = bid - 4096;
    int mat = idx >> 7, rem = idx & 127;
    int half = rem >> 6, t = rem & 63;
    int k0 = (t >> 1) * 32, n0 = (t & 1) * 32;
    const float* W = mat == 0 ? w1 : (mat == 1 ? a1 : g1);
    const float* mx = mat == 0 ? mw : (mat == 1 ? ma : mg);
#pragma unroll
    for (int i = 0; i < 4; i++) {
      int k = k0 + ty + i * 8;
      float s = half == 0 ? (1.f + mx[k]) : (-mx[k]);
      tile[ty + i * 8][tx] = (bf16)(s * W[(long)k * 64 + n0 + tx]);
    }
    __syncthreads();
#pragma unroll
    for (int i = 0; i < 4; i++)
      Bcat[(long)(mat * 64 + n0 + ty + i * 8) * 2048 + half * 1024 + k0 + tx] =
          tile[tx][ty + i * 8];
  } else if (bid < 4544) {
    int t = bid - 4480;
    int k0 = (t >> 5) * 32, n0 = (t & 31) * 32;
#pragma unroll
    for (int i = 0; i < 4; i++)
      tile[ty + i * 8][tx] = (bf16)g2[(long)(k0 + ty + i * 8) * 1024 + n0 + tx];
    __syncthreads();
#pragma unroll
    for (int i = 0; i < 4; i++)
      g2T[(long)(n0 + ty + i * 8) * 64 + k0 + tx] = tile[tx][ty + i * 8];
  } else {
#pragma unroll
    for (int rep = 0; rep < 4; rep++) {
      int idx = rep * 256 + tid;  // 0..1023
      int k = idx >> 4, h = idx & 15;
      w2T[h * 64 + k] = (bf16)w2[idx];
      a2T[h * 64 + k] = (bf16)a2[idx];
    }
    if (tid < 64) zpad[tid] = 0.f;
  }
}

// ---------------- big GEMM: 128x128 tile, BK=64, XOR-swizzled LDS ----------------
// A bf16 [M,apitch], BT bf16 [N,K]. 4 waves of 64x64. ACT: 0 none, 1 sigmoid.
template <int ACT, typename OT>
__global__ __launch_bounds__(256) void gemm128_kern(
    const bf16* __restrict__ A0, const bf16* __restrict__ A1, const bf16* __restrict__ A2,
    int apitch,
    const bf16* __restrict__ BT0, const bf16* __restrict__ BT1, const bf16* __restrict__ BT2,
    OT* __restrict__ out0, OT* __restrict__ out1, OT* __restrict__ out2,
    int opitch, int K, int nbpm) {
  int by = blockIdx.y;
  int mat = by / nbpm;
  int ncol0 = (by % nbpm) * 128;
  const bf16* Am = mat == 0 ? A0 : (mat == 1 ? A1 : A2);
  const bf16* BTm = mat == 0 ? BT0 : (mat == 1 ? BT1 : BT2);
  OT* out = mat == 0 ? out0 : (mat == 1 ? out1 : out2);
  int m0 = blockIdx.x * 128;

  __shared__ bf16 Al[128 * 64];  // [row][64], swizzled k-chunks
  __shared__ bf16 Bl[128 * 64];

  int tid = threadIdx.x;
  int w = tid >> 6, lane = tid & 63, quad = lane >> 4, lr = lane & 15;
  int wm = (w & 1) * 64, wn = (w >> 1) * 64;

  f32x4 acc[4][4] = {};

  // staging: chunk c = s*256 + tid; row = c>>3 (=s*32 + tid>>3), slot = c&7.
  // thread loads global k-chunk (slot ^ (row&7)) so LDS[row][slot] = G[row][slot^row&7].
  int r0 = tid >> 3;
  int slot = tid & 7;
  int kg = (slot ^ (r0 & 7)) * 8;
  const bf16* ag = Am + (long)(m0 + r0) * apitch + kg;
  const bf16* bg = BTm + (long)(ncol0 + r0) * K + kg;
  long astep = (long)32 * apitch;
  long bstep = (long)32 * K;
  bf16* la = Al + w * 512;   // + s*2048 per issue
  bf16* lb = Bl + w * 512;

  for (int k0 = 0; k0 < K; k0 += 64) {
#pragma unroll
    for (int s = 0; s < 4; s++) gl_lds16(ag + s * astep, la + s * 2048);
#pragma unroll
    for (int s = 0; s < 4; s++) gl_lds16(bg + s * bstep, lb + s * 2048);
    ag += 64; bg += 64;
    __syncthreads();
#pragma unroll
    for (int ko = 0; ko < 2; ko++) {
      bf16x8 af[4], bff[4];
#pragma unroll
      for (int i = 0; i < 4; i++) {
        int ra = wm + i * 16 + lr;
        af[i] = *(const bf16x8*)&Al[ra * 64 + (((ko * 4 + quad) ^ (ra & 7)) * 8)];
      }
#pragma unroll
      for (int j = 0; j < 4; j++) {
        int rb = wn + j * 16 + lr;
        bff[j] = *(const bf16x8*)&Bl[rb * 64 + (((ko * 4 + quad) ^ (rb & 7)) * 8)];
      }
#pragma unroll
      for (int i = 0; i < 4; i++)
#pragma unroll
        for (int j = 0; j < 4; j++)
          acc[i][j] = __builtin_amdgcn_mfma_f32_16x16x32_bf16(af[i], bff[j], acc[i][j], 0, 0, 0);
    }
    __syncthreads();
  }
#pragma unroll
  for (int i = 0; i < 4; i++)
#pragma unroll
    for (int j = 0; j < 4; j++)
#pragma unroll
      for (int rg = 0; rg < 4; rg++) {
        int row = m0 + wm + i * 16 + quad * 4 + rg;
        int col = ncol0 + wn + j * 16 + lr;
        float v = acc[i][j][rg];
        if (ACT == 1) v = sigmf(v);
        out[(long)row * opitch + col] = (OT)v;
      }
}

// ---------------- stage1+stage2: t1g=tanh g; w/a dots fused ----------------
// [M,2048]@[2048,192]; 64-row blocks; epilogue computes w_arr/a_arr via LDS dots.
__global__ __launch_bounds__(256) void stage1_kern(
    const bf16* __restrict__ xbf, const bf16* __restrict__ Bcat,
    const float* __restrict__ zpad, const bf16* __restrict__ w2T, const bf16* __restrict__ a2T,
    const float* __restrict__ w0, const float* __restrict__ a0,
    bf16* __restrict__ t1g, float* __restrict__ w_arr, float* __restrict__ a_arr) {
  int m0 = blockIdx.x * 64;
  __shared__ bf16 Al[64 * 32];     // 4 KB staging
  __shared__ bf16 Bl[192 * 32];    // 12 KB staging
  __shared__ bf16 Lt1[64 * 128];   // 16 KB tanh(w|a) tile

  int tid = threadIdx.x;
  int w = tid >> 6, lane = tid & 63, quad = lane >> 4, lr = lane & 15;
  int wm = w * 16;

  f32x4 acc[12] = {};

  int r0 = tid >> 2, kc0 = (tid & 3) * 8;
  int m = m0 + r0;
  const bf16* asrc = xbf + (long)m * CDIM + kc0;
  bool firstrow = (m & (TSEQ - 1)) == 0;
  const bf16* psrc = firstrow ? (const bf16*)zpad : xbf + (long)(m - 1) * CDIM + kc0;
  int pstep = firstrow ? 0 : 32;
  const bf16* bs0 = Bcat + (long)(r0)       * 2048 + kc0;
  const bf16* bs1 = Bcat + (long)(r0 + 64)  * 2048 + kc0;
  const bf16* bs2 = Bcat + (long)(r0 + 128) * 2048 + kc0;
  bf16* la = Al + w * 512;
  bf16* lb0 = Bl + w * 512;
  bf16* lb1 = Bl + 2048 + w * 512;
  bf16* lb2 = Bl + 4096 + w * 512;

#pragma unroll 1
  for (int kk = 0; kk < 64; kk++) {
    if (kk < 32) {
      gl_lds16(asrc, la);
      asrc += 32;
    } else {
      gl_lds16(psrc, la);
      psrc += pstep;
    }
    gl_lds16(bs0, lb0);
    gl_lds16(bs1, lb1);
    gl_lds16(bs2, lb2);
    bs0 += 32; bs1 += 32; bs2 += 32;
    __syncthreads();
    bf16x8 af = *(const bf16x8*)&Al[(wm + lr) * 32 + quad * 8];
#pragma unroll
    for (int nf = 0; nf < 12; nf++) {
      bf16x8 bff = *(const bf16x8*)&Bl[(nf * 16 + lr) * 32 + quad * 8];
      acc[nf] = __builtin_amdgcn_mfma_f32_16x16x32_bf16(af, bff, acc[nf], 0, 0, 0);
    }
    __syncthreads();
  }
  // w/a parts -> LDS; g part -> global t1g
#pragma unroll
  for (int nf = 0; nf < 12; nf++)
#pragma unroll
    for (int rg = 0; rg < 4; rg++) {
      int row = wm + quad * 4 + rg;
      float tv = tanhf(acc[nf][rg]);
      if (nf < 8) Lt1[row * 128 + nf * 16 + lr] = (bf16)tv;
      else t1g[(long)(m0 + row) * 64 + (nf - 8) * 16 + lr] = (bf16)tv;
    }
  __syncthreads();
  // dots: idx = (row,h); dw = sum_k Lt1[row][k]*w2T[h][k], da over k+64
#pragma unroll
  for (int rep = 0; rep < 4; rep++) {
    int idx = rep * 256 + tid;
    int row = idx >> 4, h = idx & 15;
    const bf16* rw = &Lt1[row * 128];
    const bf16* ra = rw + 64;
    const bf16* ww = w2T + h * 64;
    const bf16* aw = a2T + h * 64;
    float dw = 0.f, da = 0.f;
#pragma unroll
    for (int k = 0; k < 64; k++) {
      dw += (float)rw[k] * (float)ww[k];
      da += (float)ra[k] * (float)aw[k];
    }
    w_arr[h * TBTOK + m0 + row] = 0.60653066f * sigmf(w0[h] + dw);
    a_arr[h * TBTOK + m0 + row] = sigmf(a0[h] + da);
  }
}

// ---------------- scan pass1: fused prep + local chunk scan + cumprod -----------
__global__ __launch_bounds__(256) void scan1_kern(
    const bf16* __restrict__ k_buf, const bf16* __restrict__ v_buf, const bf16* __restrict__ r_buf,
    const float* __restrict__ k_k, const float* __restrict__ r_k,
    const float* __restrict__ a_arr, const float* __restrict__ w_arr,
    float* __restrict__ kv2, float* __restrict__ Parr, float* __restrict__ bonus) {
  int wid = blockIdx.x * 4 + (threadIdx.x >> 6);
  int lane = threadIdx.x & 63;
  int bh = wid >> 5, c = wid & 31;
  int b = bh >> 4, h = bh & 15;
  int mstart = b * TSEQ + c * CHUNK;
  int kc = h * 64 + lane;
  float kkc = k_k[kc], rkc = r_k[kc];
  float st = 0.f, cw = 1.f;
  long mbase = (long)mstart * CDIM + kc;
  int hm = h * TBTOK + mstart;
  long sbase = ((long)hm) * 64 + lane;
  float kf = (float)k_buf[mbase] * kkc;
  float vf = (float)v_buf[mbase];
  float rf = (float)r_buf[mbase];
  float af = a_arr[hm];
  float wt = w_arr[hm];
  for (int t = 0; t < CHUNK; t++) {
    float kf_n = 0.f, vf_n = 0.f, rf_n = 0.f, af_n = 0.f, wt_n = 0.f;
    if (t < CHUNK - 1) {
      kf_n = (float)k_buf[mbase + CDIM] * kkc;
      vf_n = (float)v_buf[mbase + CDIM];
      rf_n = (float)r_buf[mbase + CDIM];
      af_n = a_arr[hm + 1];
      wt_n = w_arr[hm + 1];
    }
    float ss = wredsum(kf * kf);
    float kkn = kf / fmaxf(sqrtf(ss), 1e-12f);
    st = st * wt + kkn * vf * af;
    kv2[sbase] = st;
    cw *= wt;
    float bs = wredsum(rf * kkn * rkc);
    if (lane == 0) {
      Parr[hm] = cw;
      bonus[(mstart + t) * HN + h] = bs;
    }
    kf = kf_n; vf = vf_n; rf = rf_n; af = af_n; wt = wt_n;
    mbase += CDIM; hm += 1; sbase += 64;
  }
}

// ---------------- scan pass2: serial carry scan over chunks ----------------
__global__ __launch_bounds__(64) void scan2_kern(const float* __restrict__ kv2,
                                                 const float* __restrict__ Parr,
                                                 float* __restrict__ carry) {
  int bh = blockIdx.x;  // 128: h = bh>>3, b = bh&7
  int h = bh >> 3, b = bh & 7;
  int lane = threadIdx.x;
  float S = 0.f;
  for (int c = 0; c < NCH; c++) {
    carry[(((h * 8 + b) * NCH) + c) * 64 + lane] = S;
    int mlast = b * TSEQ + c * CHUNK + (CHUNK - 1);
    float L = kv2[((long)(h * TBTOK + mlast)) * 64 + lane];
    float pw = Parr[h * TBTOK + mlast];
    S = L + pw * S;
  }
}

// ---------------- gate_post: g = sigmoid(t1g @ g2), fused WKV fixup + groupnorm ----
__global__ __launch_bounds__(256) void gate_post_kern(
    const bf16* __restrict__ t1g, const bf16* __restrict__ g2T,
    const float* __restrict__ kv2, const float* __restrict__ Parr,
    const float* __restrict__ carry, const float* __restrict__ bonus,
    bf16* __restrict__ r_buf, const bf16* __restrict__ v_buf,
    const float* __restrict__ ln_w, const float* __restrict__ ln_b) {
  int ncol0 = blockIdx.y * 128;
  int m0 = blockIdx.x * 128;

  __shared__ bf16 Al[128 * 32];
  __shared__ bf16 Bl[128 * 32];

  int tid = threadIdx.x;
  int w = tid >> 6, lane = tid & 63, quad = lane >> 4, lr = lane & 15;
  int wm = (w & 1) * 64, wn = (w >> 1) * 64;

  f32x4 acc[4][4] = {};

  int r0 = tid >> 2, kc0 = (tid & 3) * 8;
  const bf16* ag0 = t1g + (long)(m0 + r0) * 64 + kc0;
  const bf16* ag1 = ag0 + (long)64 * 64;
  const bf16* bg0 = g2T + (long)(ncol0 + r0) * 64 + kc0;
  const bf16* bg1 = bg0 + (long)64 * 64;
  bf16* la0 = Al + w * 512;
  bf16* la1 = Al + 2048 + w * 512;
  bf16* lb0 = Bl + w * 512;
  bf16* lb1 = Bl + 2048 + w * 512;

  for (int k0 = 0; k0 < 64; k0 += 32) {
    gl_lds16(ag0, la0);
    gl_lds16(ag1, la1);
    gl_lds16(bg0, lb0);
    gl_lds16(bg1, lb1);
    ag0 += 32; ag1 += 32; bg0 += 32; bg1 += 32;
    __syncthreads();
    bf16x8 af[4], bff[4];
#pragma unroll
    for (int i = 0; i < 4; i++) af[i] = *(const bf16x8*)&Al[(wm + i * 16 + lr) * 32 + quad * 8];
#pragma unroll
    for (int j = 0; j < 4; j++) bff[j] = *(const bf16x8*)&Bl[(wn + j * 16 + lr) * 32 + quad * 8];
#pragma unroll
    for (int i = 0; i < 4; i++)
#pragma unroll
      for (int j = 0; j < 4; j++)
        acc[i][j] = __builtin_amdgcn_mfma_f32_16x16x32_bf16(af[i], bff[j], acc[i][j], 0, 0, 0);
    __syncthreads();
  }

  int col0 = ncol0 + wn;
  int h = col0 >> 6;
  int b = m0 >> 11;
  int ch = ((m0 + wm) & (TSEQ - 1)) >> 6;
  float cy[4], lnwv[4], lnbv[4];
#pragma unroll
  for (int j = 0; j < 4; j++) {
    int d = j * 16 + lr;
    cy[j] = carry[((h * 8 + b) * NCH + ch) * 64 + d];
    lnwv[j] = ln_w[col0 + d];
    lnbv[j] = ln_b[col0 + d];
  }
#pragma unroll
  for (int i = 0; i < 4; i++)
#pragma unroll
    for (int rg = 0; rg < 4; rg++) {
      int row = m0 + wm + i * 16 + quad * 4 + rg;
      float pw = Parr[h * TBTOK + row];
      float bs = bonus[row * HN + h];
      long kvb = ((long)h * TBTOK + row) * 64;
      long rb = (long)row * CDIM + col0;
      float xw[4];
#pragma unroll
      for (int j = 0; j < 4; j++) {
        int d = j * 16 + lr;
        float st = kv2[kvb + d] + pw * cy[j];
        float rf = (float)r_buf[rb + d];
        float vf = (float)v_buf[rb + d];
        xw[j] = st * rf + bs * vf;
      }
      float sum = xw[0] + xw[1] + xw[2] + xw[3];
      float mn = qredsum(sum) * (1.f / 64.f);
      float vs = 0.f;
#pragma unroll
      for (int j = 0; j < 4; j++) {
        xw[j] -= mn;
        vs += xw[j] * xw[j];
      }
      float var = qredsum(vs) * (1.f / 64.f);
      float rq = rsqrtf(var + 1e-5f);
#pragma unroll
      for (int j = 0; j < 4; j++) {
        int d = j * 16 + lr;
        float y = xw[j] * rq * lnwv[j] + lnbv[j];
        float gv = sigmf(acc[i][j][rg]);
        r_buf[rb + d] = (bf16)(y * gv);
      }
    }
}

extern "C" void kernel_launch(void* const* d_in, const int* in_sizes, int n_in,
                              void* d_out, int out_size, void* d_ws, size_t ws_size,
                              hipStream_t stream) {
  const float* x    = (const float*)d_in[0];
  const float* x_r  = (const float*)d_in[1];
  const float* x_w  = (const float*)d_in[2];
  const float* x_k  = (const float*)d_in[3];
  const float* x_v  = (const float*)d_in[4];
  const float* x_a  = (const float*)d_in[5];
  const float* x_g  = (const float*)d_in[6];
  const float* w0   = (const float*)d_in[7];
  const float* w1   = (const float*)d_in[8];
  const float* w2   = (const float*)d_in[9];
  const float* a0   = (const float*)d_in[10];
  const float* a1   = (const float*)d_in[11];
  const float* a2   = (const float*)d_in[12];
  // v0,v1,v2 (13,14,15) unused: v_res_gate is a no-op in the reference
  const float* g1   = (const float*)d_in[16];
  const float* g2   = (const float*)d_in[17];
  const float* k_k  = (const float*)d_in[18];
  const float* r_k  = (const float*)d_in[19];
  const float* Wr   = (const float*)d_in[20];
  const float* Wk   = (const float*)d_in[21];
  const float* Wv   = (const float*)d_in[22];
  const float* Wo   = (const float*)d_in[23];
  const float* ln_w = (const float*)d_in[24];
  const float* ln_b = (const float*)d_in[25];
  float* out = (float*)d_out;

  char* p = (char*)d_ws;
  auto carve = [&](size_t bytes) {
    void* r = (void*)p;
    p += (bytes + 255) & ~(size_t)255;
    return r;
  };
  bf16* WrT = (bf16*)carve(1024 * 1024 * 2);
  bf16* WkT = (bf16*)carve(1024 * 1024 * 2);
  bf16* WvT = (bf16*)carve(1024 * 1024 * 2);
  bf16* WoT = (bf16*)carve(1024 * 1024 * 2);
  bf16* Bcat = (bf16*)carve(192 * 2048 * 2);
  bf16* g2T  = (bf16*)carve(1024 * 64 * 2);
  bf16* w2T  = (bf16*)carve(16 * 64 * 2);
  bf16* a2T  = (bf16*)carve(16 * 64 * 2);
  float* zpad = (float*)carve(64 * 4);
  bf16* t1g   = (bf16*)carve((size_t)TBTOK * 64 * 2);
  bf16* r_buf = (bf16*)carve((size_t)TBTOK * CDIM * 2);
  bf16* k_buf = (bf16*)carve((size_t)TBTOK * CDIM * 2);
  bf16* v_buf = (bf16*)carve((size_t)TBTOK * CDIM * 2);
  float* w_arr = (float*)carve((size_t)TBTOK * HN * 4);
  float* a_arr = (float*)carve((size_t)TBTOK * HN * 4);
  float* bonus = (float*)carve((size_t)TBTOK * HN * 4);
  float* Parr  = (float*)carve((size_t)TBTOK * HN * 4);
  float* carry = (float*)carve((size_t)128 * NCH * 64 * 4);
  bf16* xr  = (bf16*)carve((size_t)TBTOK * CDIM * 2);
  bf16* xk  = (bf16*)carve((size_t)TBTOK * CDIM * 2);
  bf16* xv  = (bf16*)carve((size_t)TBTOK * CDIM * 2);
  bf16* xbf = (bf16*)carve((size_t)TBTOK * CDIM * 2);
  float* kv2 = (float*)xv;  // 64MB = xv+xbf, dead before scan1

  // 1. mixcvt + all weight prep
  prep_kern<<<dim3(8192 + 4545), 256, 0, stream>>>(
      x, x_r, x_k, x_v, xr, xk, xv, xbf,
      Wr, Wk, Wv, Wo, w1, a1, g1, x_w, x_a, x_g, g2, w2, a2,
      WrT, WkT, WvT, WoT, Bcat, g2T, w2T, a2T, zpad);
  // 2. LoRA stage1+stage2 fused
  stage1_kern<<<dim3(TBTOK / 64), 256, 0, stream>>>(
      xbf, Bcat, zpad, w2T, a2T, w0, a0, t1g, w_arr, a_arr);
  // 3. r,k,v projections (BK=64, swizzled)
  gemm128_kern<0, bf16><<<dim3(TBTOK / 128, 24), 256, 0, stream>>>(
      xr, xk, xv, CDIM, WrT, WkT, WvT,
      r_buf, k_buf, v_buf, CDIM, 1024, 8);
  // 4-5. chunked WKV scan
  scan1_kern<<<dim3(128 * NCH / 4), 256, 0, stream>>>(
      k_buf, v_buf, r_buf, k_k, r_k, a_arr, w_arr, kv2, Parr, bonus);
  scan2_kern<<<dim3(128), 64, 0, stream>>>(kv2, Parr, carry);
  // 6. gate GEMM + fused fixup/groupnorm/gating -> an (into r_buf)
  gate_post_kern<<<dim3(TBTOK / 128, 8), 256, 0, stream>>>(
      t1g, g2T, kv2, Parr, carry, bonus, r_buf, v_buf, ln_w, ln_b);
  // 7. out = an @ Wo  (f32 output)
  gemm128_kern<0, float><<<dim3(TBTOK / 128, 8), 256, 0, stream>>>(
      r_buf, r_buf, r_buf, CDIM, WoT, WoT, WoT,
      out, out, out, CDIM, 1024, 8);
}

// Round 7
// 569.059 us; speedup vs baseline: 1.2498x; 1.0262x over previous
//
#include <hip/hip_runtime.h>

// RWKV v7 TimeMix forward, MI355X gfx950.
// B=8 T=2048 C=1024 H=16 D=64 DLOW=64. I/O f32, internal bf16 MFMA + f32 scan.
// R7: vectorized gate_post phase-2 (LDS transpose), CHUNK=32 + carry=Lend approx
//     (w <= e^-0.5 => P_chunk <= e^-16; scan2 eliminated), stage1 2-way split,
//     XCD-friendly GEMM grids. 6 launches.

typedef __bf16 bf16;
typedef __attribute__((ext_vector_type(8))) __bf16 bf16x8;
typedef __attribute__((ext_vector_type(4))) float f32x4;

#define TBTOK 16384   // B*T
#define TSEQ  2048
#define CDIM  1024
#define HN    16
#define CHUNK 32
#define NCH   64      // TSEQ / CHUNK

__device__ __forceinline__ float wredsum(float v) {
#pragma unroll
  for (int o = 32; o > 0; o >>= 1) v += __shfl_xor(v, o, 64);
  return v;
}
__device__ __forceinline__ float redsum8(float v) {  // 8 consecutive lanes
#pragma unroll
  for (int o = 4; o > 0; o >>= 1) v += __shfl_xor(v, o, 64);
  return v;
}
__device__ __forceinline__ float sigmf(float x) { return 1.f / (1.f + expf(-x)); }

// async global->LDS, 16 bytes/lane. LDS base wave-uniform (HW adds lane*16).
__device__ __forceinline__ void gl_lds16(const bf16* g, bf16* l) {
  __builtin_amdgcn_global_load_lds(
      (const __attribute__((address_space(1))) unsigned int*)g,
      (__attribute__((address_space(3))) unsigned int*)l, 16, 0, 0);
}

// ---------------- prep: mixcvt (blocks 0..8191) + all weight transposes ----------
__global__ __launch_bounds__(256) void prep_kern(
    const float* __restrict__ x, const float* __restrict__ mr,
    const float* __restrict__ mk, const float* __restrict__ mv,
    bf16* __restrict__ xr, bf16* __restrict__ xk, bf16* __restrict__ xv,
    bf16* __restrict__ xbf,
    const float* __restrict__ Wr, const float* __restrict__ Wk,
    const float* __restrict__ Wv, const float* __restrict__ Wo,
    const float* __restrict__ w1, const float* __restrict__ a1, const float* __restrict__ g1,
    const float* __restrict__ mw, const float* __restrict__ ma, const float* __restrict__ mg,
    const float* __restrict__ g2, const float* __restrict__ w2, const float* __restrict__ a2,
    bf16* __restrict__ WrT, bf16* __restrict__ WkT, bf16* __restrict__ WvT, bf16* __restrict__ WoT,
    bf16* __restrict__ Bcat, bf16* __restrict__ g2T,
    bf16* __restrict__ w2T, bf16* __restrict__ a2T, float* __restrict__ zpad) {
  int bid0 = blockIdx.x;
  int tid = threadIdx.x;
  if (bid0 < 8192) {
    long i8 = ((long)bid0 * 256 + tid) * 8;
    int m = (int)(i8 >> 10);
    int c = (int)(i8 & 1023);
    f32x4 x0 = *(const f32x4*)(x + i8);
    f32x4 x1 = *(const f32x4*)(x + i8 + 4);
    f32x4 p0 = {0.f, 0.f, 0.f, 0.f}, p1 = {0.f, 0.f, 0.f, 0.f};
    if ((m & (TSEQ - 1)) != 0) {
      p0 = *(const f32x4*)(x + i8 - CDIM);
      p1 = *(const f32x4*)(x + i8 - CDIM + 4);
    }
    f32x4 r0 = *(const f32x4*)(mr + c), r1 = *(const f32x4*)(mr + c + 4);
    f32x4 k0 = *(const f32x4*)(mk + c), k1 = *(const f32x4*)(mk + c + 4);
    f32x4 v0 = *(const f32x4*)(mv + c), v1 = *(const f32x4*)(mv + c + 4);
    bf16x8 or_, ok_, ov_, ox_;
#pragma unroll
    for (int j = 0; j < 4; j++) {
      float s0 = x0[j] - p0[j], s1 = x1[j] - p1[j];
      or_[j] = (bf16)(x0[j] + s0 * r0[j]); or_[4 + j] = (bf16)(x1[j] + s1 * r1[j]);
      ok_[j] = (bf16)(x0[j] + s0 * k0[j]); ok_[4 + j] = (bf16)(x1[j] + s1 * k1[j]);
      ov_[j] = (bf16)(x0[j] + s0 * v0[j]); ov_[4 + j] = (bf16)(x1[j] + s1 * v1[j]);
      ox_[j] = (bf16)x0[j];                ox_[4 + j] = (bf16)x1[j];
    }
    *(bf16x8*)(xr + i8) = or_;
    *(bf16x8*)(xk + i8) = ok_;
    *(bf16x8*)(xv + i8) = ov_;
    *(bf16x8*)(xbf + i8) = ox_;
    return;
  }
  int bid = bid0 - 8192;
  int tx = tid & 31, ty = tid >> 5;  // 32 x 8
  __shared__ bf16 tile[32][33];
  if (bid < 4096) {
    int sel = bid >> 10, t = bid & 1023;
    int k0 = (t >> 5) * 32, n0 = (t & 31) * 32;
    const float* src = sel == 0 ? Wr : (sel == 1 ? Wk : (sel == 2 ? Wv : Wo));
    bf16* dst = sel == 0 ? WrT : (sel == 1 ? WkT : (sel == 2 ? WvT : WoT));
#pragma unroll
    for (int i = 0; i < 4; i++)
      tile[ty + i * 8][tx] = (bf16)src[(long)(k0 + ty + i * 8) * 1024 + n0 + tx];
    __syncthreads();
#pragma unroll
    for (int i = 0; i < 4; i++)
      dst[(long)(n0 + ty + i * 8) * 1024 + k0 + tx] = tile[tx][ty + i * 8];
  } else if (bid < 4480) {
    int idx = bid - 4096;
    int mat = idx >> 7, rem = idx & 127;
    int half = rem >> 6, t = rem & 63;
    int k0 = (t >> 1) * 32, n0 = (t & 1) * 32;
    const float* W = mat == 0 ? w1 : (mat == 1 ? a1 : g1);
    const float* mx = mat == 0 ? mw : (mat == 1 ? ma : mg);
#pragma unroll
    for (int i = 0; i < 4; i++) {
      int k = k0 + ty + i * 8;
      float s = half == 0 ? (1.f + mx[k]) : (-mx[k]);
      tile[ty + i * 8][tx] = (bf16)(s * W[(long)k * 64 + n0 + tx]);
    }
    __syncthreads();
#pragma unroll
    for (int i = 0; i < 4; i++)
      Bcat[(long)(mat * 64 + n0 + ty + i * 8) * 2048 + half * 1024 + k0 + tx] =
          tile[tx][ty + i * 8];
  } else if (bid < 4544) {
    int t = bid - 4480;
    int k0 = (t >> 5) * 32, n0 = (t & 31) * 32;
#pragma unroll
    for (int i = 0; i < 4; i++)
      tile[ty + i * 8][tx] = (bf16)g2[(long)(k0 + ty + i * 8) * 1024 + n0 + tx];
    __syncthreads();
#pragma unroll
    for (int i = 0; i < 4; i++)
      g2T[(long)(n0 + ty + i * 8) * 64 + k0 + tx] = tile[tx][ty + i * 8];
  } else {
#pragma unroll
    for (int rep = 0; rep < 4; rep++) {
      int idx = rep * 256 + tid;  // 0..1023
      int k = idx >> 4, h = idx & 15;
      w2T[h * 64 + k] = (bf16)w2[idx];
      a2T[h * 64 + k] = (bf16)a2[idx];
    }
    if (tid < 64) zpad[tid] = 0.f;
  }
}

// ---------------- big GEMM: 128x128 tile, BK=64, XOR-swizzled LDS ----------------
// grid = (nmats*nbpm, mtiles) so each XCD keeps its B-tiles L2-resident.
template <int ACT, typename OT>
__global__ __launch_bounds__(256) void gemm128_kern(
    const bf16* __restrict__ A0, const bf16* __restrict__ A1, const bf16* __restrict__ A2,
    int apitch,
    const bf16* __restrict__ BT0, const bf16* __restrict__ BT1, const bf16* __restrict__ BT2,
    OT* __restrict__ out0, OT* __restrict__ out1, OT* __restrict__ out2,
    int opitch, int K, int nbpm) {
  int bx = blockIdx.x;
  int mat = bx / nbpm;
  int ncol0 = (bx % nbpm) * 128;
  const bf16* Am = mat == 0 ? A0 : (mat == 1 ? A1 : A2);
  const bf16* BTm = mat == 0 ? BT0 : (mat == 1 ? BT1 : BT2);
  OT* out = mat == 0 ? out0 : (mat == 1 ? out1 : out2);
  int m0 = blockIdx.y * 128;

  __shared__ bf16 Al[128 * 64];  // [row][64], swizzled k-chunks
  __shared__ bf16 Bl[128 * 64];

  int tid = threadIdx.x;
  int w = tid >> 6, lane = tid & 63, quad = lane >> 4, lr = lane & 15;
  int wm = (w & 1) * 64, wn = (w >> 1) * 64;

  f32x4 acc[4][4] = {};

  int r0 = tid >> 3;
  int slot = tid & 7;
  int kg = (slot ^ (r0 & 7)) * 8;
  const bf16* ag = Am + (long)(m0 + r0) * apitch + kg;
  const bf16* bg = BTm + (long)(ncol0 + r0) * K + kg;
  long astep = (long)32 * apitch;
  long bstep = (long)32 * K;
  bf16* la = Al + w * 512;
  bf16* lb = Bl + w * 512;

  for (int k0 = 0; k0 < K; k0 += 64) {
#pragma unroll
    for (int s = 0; s < 4; s++) gl_lds16(ag + s * astep, la + s * 2048);
#pragma unroll
    for (int s = 0; s < 4; s++) gl_lds16(bg + s * bstep, lb + s * 2048);
    ag += 64; bg += 64;
    __syncthreads();
#pragma unroll
    for (int ko = 0; ko < 2; ko++) {
      bf16x8 af[4], bff[4];
#pragma unroll
      for (int i = 0; i < 4; i++) {
        int ra = wm + i * 16 + lr;
        af[i] = *(const bf16x8*)&Al[ra * 64 + (((ko * 4 + quad) ^ (ra & 7)) * 8)];
      }
#pragma unroll
      for (int j = 0; j < 4; j++) {
        int rb = wn + j * 16 + lr;
        bff[j] = *(const bf16x8*)&Bl[rb * 64 + (((ko * 4 + quad) ^ (rb & 7)) * 8)];
      }
#pragma unroll
      for (int i = 0; i < 4; i++)
#pragma unroll
        for (int j = 0; j < 4; j++)
          acc[i][j] = __builtin_amdgcn_mfma_f32_16x16x32_bf16(af[i], bff[j], acc[i][j], 0, 0, 0);
    }
    __syncthreads();
  }
#pragma unroll
  for (int i = 0; i < 4; i++)
#pragma unroll
    for (int j = 0; j < 4; j++)
#pragma unroll
      for (int rg = 0; rg < 4; rg++) {
        int row = m0 + wm + i * 16 + quad * 4 + rg;
        int col = ncol0 + wn + j * 16 + lr;
        float v = acc[i][j][rg];
        if (ACT == 1) v = sigmf(v);
        out[(long)row * opitch + col] = (OT)v;
      }
}

// ---------------- stage1: [x|xprev]@Bcat^T; part0 = w+a cols (+fused dots), part1 = g ----
__global__ __launch_bounds__(256) void stage1_kern(
    const bf16* __restrict__ xbf, const bf16* __restrict__ Bcat,
    const float* __restrict__ zpad, const bf16* __restrict__ w2T, const bf16* __restrict__ a2T,
    const float* __restrict__ w0, const float* __restrict__ a0,
    bf16* __restrict__ t1g, float* __restrict__ w_arr, float* __restrict__ a_arr) {
  int m0 = blockIdx.x * 64;
  int part = blockIdx.y;  // 0: cols 0..127 (w,a) ; 1: cols 128..191 (g)
  __shared__ bf16 Al[64 * 32];     // 4 KB
  __shared__ bf16 Bl[128 * 32];    // 8 KB
  __shared__ bf16 Lt1[64 * 136];   // 17 KB (part0 only)

  int tid = threadIdx.x;
  int w = tid >> 6, lane = tid & 63, quad = lane >> 4, lr = lane & 15;
  int wm = w * 16;

  int r0 = tid >> 2, kc0 = (tid & 3) * 8;
  int m = m0 + r0;
  const bf16* asrc = xbf + (long)m * CDIM + kc0;
  bool firstrow = (m & (TSEQ - 1)) == 0;
  const bf16* psrc = firstrow ? (const bf16*)zpad : xbf + (long)(m - 1) * CDIM + kc0;
  int pstep = firstrow ? 0 : 32;
  int brow0 = part ? 128 : 0;
  const bf16* bs0 = Bcat + (long)(brow0 + r0) * 2048 + kc0;
  const bf16* bs1 = bs0 + (long)64 * 2048;
  bf16* la = Al + w * 512;
  bf16* lb0 = Bl + w * 512;
  bf16* lb1 = Bl + 2048 + w * 512;

  if (part == 0) {
    f32x4 acc[8] = {};
#pragma unroll 1
    for (int kk = 0; kk < 64; kk++) {
      if (kk < 32) { gl_lds16(asrc, la); asrc += 32; }
      else         { gl_lds16(psrc, la); psrc += pstep; }
      gl_lds16(bs0, lb0);
      gl_lds16(bs1, lb1);
      bs0 += 32; bs1 += 32;
      __syncthreads();
      bf16x8 af = *(const bf16x8*)&Al[(wm + lr) * 32 + quad * 8];
#pragma unroll
      for (int nf = 0; nf < 8; nf++) {
        bf16x8 bff = *(const bf16x8*)&Bl[(nf * 16 + lr) * 32 + quad * 8];
        acc[nf] = __builtin_amdgcn_mfma_f32_16x16x32_bf16(af, bff, acc[nf], 0, 0, 0);
      }
      __syncthreads();
    }
#pragma unroll
    for (int nf = 0; nf < 8; nf++)
#pragma unroll
      for (int rg = 0; rg < 4; rg++) {
        int row = wm + quad * 4 + rg;
        Lt1[row * 136 + nf * 16 + lr] = (bf16)tanhf(acc[nf][rg]);
      }
    __syncthreads();
#pragma unroll
    for (int rep = 0; rep < 4; rep++) {
      int idx = rep * 256 + tid;
      int row = idx >> 4, h = idx & 15;
      const bf16* rw = &Lt1[row * 136];
      const bf16* ra = rw + 64;
      const bf16* ww = w2T + h * 64;
      const bf16* aw = a2T + h * 64;
      float dw = 0.f, da = 0.f;
#pragma unroll
      for (int k = 0; k < 64; k++) {
        dw += (float)rw[k] * (float)ww[k];
        da += (float)ra[k] * (float)aw[k];
      }
      w_arr[h * TBTOK + m0 + row] = 0.60653066f * sigmf(w0[h] + dw);
      a_arr[h * TBTOK + m0 + row] = sigmf(a0[h] + da);
    }
  } else {
    f32x4 acc[4] = {};
#pragma unroll 1
    for (int kk = 0; kk < 64; kk++) {
      if (kk < 32) { gl_lds16(asrc, la); asrc += 32; }
      else         { gl_lds16(psrc, la); psrc += pstep; }
      gl_lds16(bs0, lb0);
      bs0 += 32;
      __syncthreads();
      bf16x8 af = *(const bf16x8*)&Al[(wm + lr) * 32 + quad * 8];
#pragma unroll
      for (int nf = 0; nf < 4; nf++) {
        bf16x8 bff = *(const bf16x8*)&Bl[(nf * 16 + lr) * 32 + quad * 8];
        acc[nf] = __builtin_amdgcn_mfma_f32_16x16x32_bf16(af, bff, acc[nf], 0, 0, 0);
      }
      __syncthreads();
    }
#pragma unroll
    for (int nf = 0; nf < 4; nf++)
#pragma unroll
      for (int rg = 0; rg < 4; rg++) {
        int row = wm + quad * 4 + rg;
        t1g[(long)(m0 + row) * 64 + nf * 16 + lr] = (bf16)tanhf(acc[nf][rg]);
      }
  }
}

// ---------------- scan1: fused prep + local 32-token scan; chunk-final -> Lend ------
// wave per (bh, chunk). 128 bh * 64 chunks = 8192 waves.
__global__ __launch_bounds__(256) void scan1_kern(
    const bf16* __restrict__ k_buf, const bf16* __restrict__ v_buf, const bf16* __restrict__ r_buf,
    const float* __restrict__ k_k, const float* __restrict__ r_k,
    const float* __restrict__ a_arr, const float* __restrict__ w_arr,
    float* __restrict__ kv2, float* __restrict__ Parr, float* __restrict__ bonus,
    float* __restrict__ Lend) {
  int wid = blockIdx.x * 4 + (threadIdx.x >> 6);
  int lane = threadIdx.x & 63;
  int bh = wid >> 6, c = wid & 63;
  int b = bh >> 4, h = bh & 15;
  int mstart = b * TSEQ + c * CHUNK;
  int kc = h * 64 + lane;
  float kkc = k_k[kc], rkc = r_k[kc];
  float st = 0.f, cw = 1.f;
  long mbase = (long)mstart * CDIM + kc;
  int hm = h * TBTOK + mstart;
  long sbase = ((long)hm) * 64 + lane;
  float kf = (float)k_buf[mbase] * kkc;
  float vf = (float)v_buf[mbase];
  float rf = (float)r_buf[mbase];
  float af = a_arr[hm];
  float wt = w_arr[hm];
  for (int t = 0; t < CHUNK; t++) {
    float kf_n = 0.f, vf_n = 0.f, rf_n = 0.f, af_n = 0.f, wt_n = 0.f;
    if (t < CHUNK - 1) {
      kf_n = (float)k_buf[mbase + CDIM] * kkc;
      vf_n = (float)v_buf[mbase + CDIM];
      rf_n = (float)r_buf[mbase + CDIM];
      af_n = a_arr[hm + 1];
      wt_n = w_arr[hm + 1];
    }
    float ss = wredsum(kf * kf);
    float kkn = kf / fmaxf(sqrtf(ss), 1e-12f);
    st = st * wt + kkn * vf * af;
    kv2[sbase] = st;
    cw *= wt;
    float bs = wredsum(rf * kkn * rkc);
    if (lane == 0) {
      Parr[hm] = cw;
      bonus[(mstart + t) * HN + h] = bs;
    }
    kf = kf_n; vf = vf_n; rf = rf_n; af = af_n; wt = wt_n;
    mbase += CDIM; hm += 1; sbase += 64;
  }
  // carry entering next chunk == this chunk's final state (P_chunk <= e^-16)
  Lend[(long)wid * 64 + lane] = st;
}

// ---------------- gate_post: g=sigmoid(t1g@g2) -> LDS; vectorized fixup+groupnorm ----
__global__ __launch_bounds__(256) void gate_post_kern(
    const bf16* __restrict__ t1g, const bf16* __restrict__ g2T,
    const float* __restrict__ kv2, const float* __restrict__ Parr,
    const float* __restrict__ Lend, const float* __restrict__ bonus,
    bf16* __restrict__ r_buf, const bf16* __restrict__ v_buf,
    const float* __restrict__ ln_w, const float* __restrict__ ln_b) {
  int ncol0 = blockIdx.x * 128;
  int m0 = blockIdx.y * 128;

  __shared__ bf16 Al[128 * 32];       // 8 KB
  __shared__ bf16 Bl[128 * 32];       // 8 KB
  __shared__ bf16 gtile[128 * 136];   // 34 KB

  int tid = threadIdx.x;
  int w = tid >> 6, lane = tid & 63, quad = lane >> 4, lr = lane & 15;
  int wm = (w & 1) * 64, wn = (w >> 1) * 64;

  f32x4 acc[4][4] = {};

  int r0 = tid >> 2, kc0 = (tid & 3) * 8;
  const bf16* ag0 = t1g + (long)(m0 + r0) * 64 + kc0;
  const bf16* ag1 = ag0 + (long)64 * 64;
  const bf16* bg0 = g2T + (long)(ncol0 + r0) * 64 + kc0;
  const bf16* bg1 = bg0 + (long)64 * 64;
  bf16* la0 = Al + w * 512;
  bf16* la1 = Al + 2048 + w * 512;
  bf16* lb0 = Bl + w * 512;
  bf16* lb1 = Bl + 2048 + w * 512;

  for (int k0 = 0; k0 < 64; k0 += 32) {
    gl_lds16(ag0, la0);
    gl_lds16(ag1, la1);
    gl_lds16(bg0, lb0);
    gl_lds16(bg1, lb1);
    ag0 += 32; ag1 += 32; bg0 += 32; bg1 += 32;
    __syncthreads();
    bf16x8 af[4], bff[4];
#pragma unroll
    for (int i = 0; i < 4; i++) af[i] = *(const bf16x8*)&Al[(wm + i * 16 + lr) * 32 + quad * 8];
#pragma unroll
    for (int j = 0; j < 4; j++) bff[j] = *(const bf16x8*)&Bl[(wn + j * 16 + lr) * 32 + quad * 8];
#pragma unroll
    for (int i = 0; i < 4; i++)
#pragma unroll
      for (int j = 0; j < 4; j++)
        acc[i][j] = __builtin_amdgcn_mfma_f32_16x16x32_bf16(af[i], bff[j], acc[i][j], 0, 0, 0);
    __syncthreads();
  }
  // phase 1b: sigmoid(gate) -> LDS tile in C-layout
#pragma unroll
  for (int i = 0; i < 4; i++)
#pragma unroll
    for (int j = 0; j < 4; j++)
#pragma unroll
      for (int rg = 0; rg < 4; rg++) {
        int row = wm + i * 16 + quad * 4 + rg;
        int col = wn + j * 16 + lr;
        gtile[row * 136 + col] = (bf16)sigmf(acc[i][j][rg]);
      }
  __syncthreads();

  // phase 2: 8 contiguous channels per thread; fully vectorized global access
  int c_loc = (tid & 15) * 8;            // 0..120
  int col_g = ncol0 + c_loc;
  int h = col_g >> 6;
  int d0 = col_g & 63;
  f32x4 lnw0 = *(const f32x4*)(ln_w + col_g);
  f32x4 lnw1 = *(const f32x4*)(ln_w + col_g + 4);
  f32x4 lnb0 = *(const f32x4*)(ln_b + col_g);
  f32x4 lnb1 = *(const f32x4*)(ln_b + col_g + 4);
#pragma unroll
  for (int jj = 0; jj < 8; jj++) {
    int row = jj * 16 + (tid >> 4);
    int row_g = m0 + row;
    int b = row_g >> 11;
    int ch = (row_g & (TSEQ - 1)) >> 5;
    long kvb = ((long)h * TBTOK + row_g) * 64 + d0;
    f32x4 st0 = *(const f32x4*)(kv2 + kvb);
    f32x4 st1 = *(const f32x4*)(kv2 + kvb + 4);
    f32x4 cy0 = {0.f, 0.f, 0.f, 0.f}, cy1 = {0.f, 0.f, 0.f, 0.f};
    if (ch != 0) {
      long lb = ((long)((b * 16 + h) * NCH + ch - 1)) * 64 + d0;
      cy0 = *(const f32x4*)(Lend + lb);
      cy1 = *(const f32x4*)(Lend + lb + 4);
    }
    float pw = Parr[h * TBTOK + row_g];
    float bs = bonus[row_g * HN + h];
    long rb = (long)row_g * CDIM + col_g;
    bf16x8 rf8 = *(const bf16x8*)(r_buf + rb);
    bf16x8 vf8 = *(const bf16x8*)(v_buf + rb);
    bf16x8 g8 = *(const bf16x8*)&gtile[row * 136 + c_loc];
    float xw[8];
#pragma unroll
    for (int q = 0; q < 4; q++) {
      xw[q]     = (st0[q] + pw * cy0[q]) * (float)rf8[q]     + bs * (float)vf8[q];
      xw[4 + q] = (st1[q] + pw * cy1[q]) * (float)rf8[4 + q] + bs * (float)vf8[4 + q];
    }
    float sum = 0.f;
#pragma unroll
    for (int q = 0; q < 8; q++) sum += xw[q];
    float mn = redsum8(sum) * (1.f / 64.f);
    float vs = 0.f;
#pragma unroll
    for (int q = 0; q < 8; q++) {
      xw[q] -= mn;
      vs += xw[q] * xw[q];
    }
    float var = redsum8(vs) * (1.f / 64.f);
    float rq = rsqrtf(var + 1e-5f);
    bf16x8 o8;
#pragma unroll
    for (int q = 0; q < 4; q++) {
      o8[q]     = (bf16)((xw[q] * rq * lnw0[q] + lnb0[q]) * (float)g8[q]);
      o8[4 + q] = (bf16)((xw[4 + q] * rq * lnw1[q] + lnb1[q]) * (float)g8[4 + q]);
    }
    *(bf16x8*)(r_buf + rb) = o8;
  }
}

extern "C" void kernel_launch(void* const* d_in, const int* in_sizes, int n_in,
                              void* d_out, int out_size, void* d_ws, size_t ws_size,
                              hipStream_t stream) {
  const float* x    = (const float*)d_in[0];
  const float* x_r  = (const float*)d_in[1];
  const float* x_w  = (const float*)d_in[2];
  const float* x_k  = (const float*)d_in[3];
  const float* x_v  = (const float*)d_in[4];
  const float* x_a  = (const float*)d_in[5];
  const float* x_g  = (const float*)d_in[6];
  const float* w0   = (const float*)d_in[7];
  const float* w1   = (const float*)d_in[8];
  const float* w2   = (const float*)d_in[9];
  const float* a0   = (const float*)d_in[10];
  const float* a1   = (const float*)d_in[11];
  const float* a2   = (const float*)d_in[12];
  // v0,v1,v2 (13,14,15) unused: v_res_gate is a no-op in the reference
  const float* g1   = (const float*)d_in[16];
  const float* g2   = (const float*)d_in[17];
  const float* k_k  = (const float*)d_in[18];
  const float* r_k  = (const float*)d_in[19];
  const float* Wr   = (const float*)d_in[20];
  const float* Wk   = (const float*)d_in[21];
  const float* Wv   = (const float*)d_in[22];
  const float* Wo   = (const float*)d_in[23];
  const float* ln_w = (const float*)d_in[24];
  const float* ln_b = (const float*)d_in[25];
  float* out = (float*)d_out;

  char* p = (char*)d_ws;
  auto carve = [&](size_t bytes) {
    void* r = (void*)p;
    p += (bytes + 255) & ~(size_t)255;
    return r;
  };
  bf16* WrT = (bf16*)carve(1024 * 1024 * 2);
  bf16* WkT = (bf16*)carve(1024 * 1024 * 2);
  bf16* WvT = (bf16*)carve(1024 * 1024 * 2);
  bf16* WoT = (bf16*)carve(1024 * 1024 * 2);
  bf16* Bcat = (bf16*)carve(192 * 2048 * 2);
  bf16* g2T  = (bf16*)carve(1024 * 64 * 2);
  bf16* w2T  = (bf16*)carve(16 * 64 * 2);
  bf16* a2T  = (bf16*)carve(16 * 64 * 2);
  float* zpad = (float*)carve(64 * 4);
  bf16* t1g   = (bf16*)carve((size_t)TBTOK * 64 * 2);
  bf16* r_buf = (bf16*)carve((size_t)TBTOK * CDIM * 2);
  bf16* k_buf = (bf16*)carve((size_t)TBTOK * CDIM * 2);
  bf16* v_buf = (bf16*)carve((size_t)TBTOK * CDIM * 2);
  float* w_arr = (float*)carve((size_t)TBTOK * HN * 4);
  float* a_arr = (float*)carve((size_t)TBTOK * HN * 4);
  float* bonus = (float*)carve((size_t)TBTOK * HN * 4);
  float* Parr  = (float*)carve((size_t)TBTOK * HN * 4);
  float* Lend  = (float*)carve((size_t)128 * NCH * 64 * 4);
  bf16* xr  = (bf16*)carve((size_t)TBTOK * CDIM * 2);
  bf16* xk  = (bf16*)carve((size_t)TBTOK * CDIM * 2);
  bf16* xv  = (bf16*)carve((size_t)TBTOK * CDIM * 2);
  bf16* xbf = (bf16*)carve((size_t)TBTOK * CDIM * 2);
  float* kv2 = (float*)xv;  // 64MB = xv+xbf, dead before scan1

  // 1. mixcvt + all weight prep
  prep_kern<<<dim3(8192 + 4545), 256, 0, stream>>>(
      x, x_r, x_k, x_v, xr, xk, xv, xbf,
      Wr, Wk, Wv, Wo, w1, a1, g1, x_w, x_a, x_g, g2, w2, a2,
      WrT, WkT, WvT, WoT, Bcat, g2T, w2T, a2T, zpad);
  // 2. LoRA stage1 (+fused stage2 dots in part 0)
  stage1_kern<<<dim3(TBTOK / 64, 2), 256, 0, stream>>>(
      xbf, Bcat, zpad, w2T, a2T, w0, a0, t1g, w_arr, a_arr);
  // 3. r,k,v projections (XCD-friendly grid: B-tiles stay L2-resident)
  gemm128_kern<0, bf16><<<dim3(24, TBTOK / 128), 256, 0, stream>>>(
      xr, xk, xv, CDIM, WrT, WkT, WvT,
      r_buf, k_buf, v_buf, CDIM, 1024, 8);
  // 4. WKV local scans (CHUNK=32; carry == prev chunk-final state)
  scan1_kern<<<dim3(128 * NCH / 4), 256, 0, stream>>>(
      k_buf, v_buf, r_buf, k_k, r_k, a_arr, w_arr, kv2, Parr, bonus, Lend);
  // 5. gate GEMM + vectorized fixup/groupnorm/gating -> an (into r_buf)
  gate_post_kern<<<dim3(8, TBTOK / 128), 256, 0, stream>>>(
      t1g, g2T, kv2, Parr, Lend, bonus, r_buf, v_buf, ln_w, ln_b);
  // 6. out = an @ Wo  (f32 output)
  gemm128_kern<0, float><<<dim3(8, TBTOK / 128), 256, 0, stream>>>(
      r_buf, r_buf, r_buf, CDIM, WoT, WoT, WoT,
      out, out, out, CDIM, 1024, 8);
}